// Round 1
// baseline (739.151 us; speedup 1.0000x reference)
//
#include <hip/hip_runtime.h>
#include <hip/hip_bf16.h>
#include <math.h>

// Problem constants
#define BT   2048      // B*T tokens
#define DD   1024      // model dim
#define HH   2048      // hidden dim
#define EE   8         // experts
#define CAP  512       // expert capacity = floor(BT*0.25)

// ---------------------------------------------------------------------------
// 1. Router: scores = x @ rw + rb ; top-2 ; softmax gates
//    one block (256 thr) per token
// ---------------------------------------------------------------------------
__global__ __launch_bounds__(256) void router_kernel(
    const float* __restrict__ x, const float* __restrict__ rw,
    const float* __restrict__ rb, int2* __restrict__ assign,
    float2* __restrict__ gates)
{
    int t   = blockIdx.x;
    int tid = threadIdx.x;
    const float* xr = x + (size_t)t * DD;

    float p[EE];
    #pragma unroll
    for (int e = 0; e < EE; ++e) p[e] = 0.f;

    for (int d = tid; d < DD; d += 256) {
        float xv = xr[d];
        const float4* wr = (const float4*)(rw + (size_t)d * EE);
        float4 w0 = wr[0], w1 = wr[1];
        p[0] += xv * w0.x; p[1] += xv * w0.y; p[2] += xv * w0.z; p[3] += xv * w0.w;
        p[4] += xv * w1.x; p[5] += xv * w1.y; p[6] += xv * w1.z; p[7] += xv * w1.w;
    }
    // wave reduce (64 lanes)
    #pragma unroll
    for (int off = 32; off; off >>= 1) {
        #pragma unroll
        for (int e = 0; e < EE; ++e) p[e] += __shfl_down(p[e], off);
    }
    __shared__ float red[4][EE];
    int wv = tid >> 6, ln = tid & 63;
    if (ln == 0) {
        #pragma unroll
        for (int e = 0; e < EE; ++e) red[wv][e] = p[e];
    }
    __syncthreads();
    if (tid == 0) {
        float s[EE];
        #pragma unroll
        for (int e = 0; e < EE; ++e)
            s[e] = red[0][e] + red[1][e] + red[2][e] + red[3][e] + rb[e];
        int i0 = 0;
        #pragma unroll
        for (int e = 1; e < EE; ++e) if (s[e] > s[i0]) i0 = e;
        int i1 = -1;
        #pragma unroll
        for (int e = 0; e < EE; ++e) {
            if (e == i0) continue;
            if (i1 < 0 || s[e] > s[i1]) i1 = e;
        }
        float e1 = __expf(s[i1] - s[i0]);
        // use precise expf for safety
        e1 = expf(s[i1] - s[i0]);
        float denom = 1.0f + e1;
        assign[t] = make_int2(i0, i1);
        gates[t]  = make_float2(1.0f / denom, e1 / denom);
    }
}

// ---------------------------------------------------------------------------
// 2. Scan: capacity assignment, exact reference cumsum semantics.
//    pos[t,0,e] = #{t'<=t : assign[t'][0]==e}
//    pos[t,1,e] = #{t'<=t, k'<=1 : assign[t'][k']==e}
//    kept iff pos < CAP. slot_tok[e][pos] = {k0_token, k1_token} (-1 = none)
//    single block of 64 lanes, 32 tokens each; shuffle prefix sums.
// ---------------------------------------------------------------------------
__global__ __launch_bounds__(64) void scan_kernel(
    const int2* __restrict__ assign, int4* __restrict__ meta,
    int2* __restrict__ slot_tok)
{
    __shared__ int c0[64][EE];
    __shared__ int cA[64][EE];
    int l = threadIdx.x;

    // init slot table to -1
    for (int i = l; i < EE * CAP; i += 64) slot_tok[i] = make_int2(-1, -1);
    #pragma unroll
    for (int e = 0; e < EE; ++e) { c0[l][e] = 0; cA[l][e] = 0; }
    __syncthreads();

    const int CH = BT / 64;       // 32 tokens per lane
    int t0 = l * CH;

    // phase A: local counts
    for (int t = t0; t < t0 + CH; ++t) {
        int2 a = assign[t];
        c0[l][a.x]++; cA[l][a.x]++; cA[l][a.y]++;
    }
    __syncthreads();

    // phase B: exclusive prefix across lanes for each of the 16 streams
    #pragma unroll
    for (int e = 0; e < EE; ++e) {
        int v = c0[l][e], inc = v;
        for (int d = 1; d < 64; d <<= 1) { int u = __shfl_up(inc, d); if (l >= d) inc += u; }
        c0[l][e] = inc - v;
        v = cA[l][e]; inc = v;
        for (int d = 1; d < 64; d <<= 1) { int u = __shfl_up(inc, d); if (l >= d) inc += u; }
        cA[l][e] = inc - v;
    }
    __syncthreads();

    // phase C: replay with global offsets
    for (int t = t0; t < t0 + CH; ++t) {
        int2 a = assign[t];
        int p0 = ++c0[l][a.x];  cA[l][a.x]++;
        int p1 = ++cA[l][a.y];
        int4 m;
        m.x = a.x; m.y = (p0 < CAP) ? p0 : -1;
        m.z = a.y; m.w = (p1 < CAP) ? p1 : -1;
        meta[t] = m;
        int* st = (int*)slot_tok;
        if (p0 < CAP) st[(a.x * CAP + p0) * 2 + 0] = t;
        if (p1 < CAP) st[(a.y * CAP + p1) * 2 + 1] = t;
    }
}

// ---------------------------------------------------------------------------
// 3. Gather: grouped[e][s] = x[tokA] + x[tokB] (either may be absent)
// ---------------------------------------------------------------------------
__global__ __launch_bounds__(256) void gather_kernel(
    const float* __restrict__ x, const int2* __restrict__ slot_tok,
    float* __restrict__ G)
{
    int es = blockIdx.x;            // e*CAP + s
    int d  = threadIdx.x * 4;
    int2 st = slot_tok[es];
    float4 r = make_float4(0.f, 0.f, 0.f, 0.f);
    if (st.x >= 0) r = *(const float4*)(x + (size_t)st.x * DD + d);
    if (st.y >= 0) {
        float4 v = *(const float4*)(x + (size_t)st.y * DD + d);
        r.x += v.x; r.y += v.y; r.z += v.z; r.w += v.w;
    }
    *(float4*)(G + (size_t)es * DD + d) = r;
}

// ---------------------------------------------------------------------------
// 4. GEMM1 (per expert): Hout = gelu_tanh( (G@w1) * (G@w2) )
//    M=CAP(512) K=DD(1024) N=HH(2048); 64x64x16 fp32 tiles, 256 thr, 4x4/thr
// ---------------------------------------------------------------------------
__global__ __launch_bounds__(256) void gemm1_kernel(
    const float* __restrict__ Gr, const float* __restrict__ W1,
    const float* __restrict__ W2, float* __restrict__ Hout)
{
    const int BM = 64, BN = 64, BK = 16;
    int e  = blockIdx.z;
    int n0 = blockIdx.x * BN;
    int m0 = blockIdx.y * BM;
    const float* A  = Gr + (size_t)e * CAP * DD;
    const float* B1 = W1 + (size_t)e * DD * HH;
    const float* B2 = W2 + (size_t)e * DD * HH;

    __shared__ float As [BK][BM + 1];
    __shared__ float Bs1[BK][BN];
    __shared__ float Bs2[BK][BN];

    int tid = threadIdx.x;
    int tx = tid & 15, ty = tid >> 4;
    float acc1[4][4] = {}, acc2[4][4] = {};

    for (int k0 = 0; k0 < DD; k0 += BK) {
        {   // A tile: each thread loads float4 along K
            int m  = tid >> 2;
            int kq = (tid & 3) * 4;
            float4 v = *(const float4*)(A + (size_t)(m0 + m) * DD + k0 + kq);
            As[kq + 0][m] = v.x; As[kq + 1][m] = v.y;
            As[kq + 2][m] = v.z; As[kq + 3][m] = v.w;
        }
        {   // B tiles: row kr, 4 cols
            int kr = tid >> 4;
            int nq = (tid & 15) * 4;
            *(float4*)&Bs1[kr][nq] = *(const float4*)(B1 + (size_t)(k0 + kr) * HH + n0 + nq);
            *(float4*)&Bs2[kr][nq] = *(const float4*)(B2 + (size_t)(k0 + kr) * HH + n0 + nq);
        }
        __syncthreads();
        #pragma unroll
        for (int kk = 0; kk < BK; ++kk) {
            float a[4], b1[4], b2[4];
            #pragma unroll
            for (int i = 0; i < 4; ++i) a[i] = As[kk][ty * 4 + i];
            #pragma unroll
            for (int j = 0; j < 4; ++j) { b1[j] = Bs1[kk][tx * 4 + j]; b2[j] = Bs2[kk][tx * 4 + j]; }
            #pragma unroll
            for (int i = 0; i < 4; ++i)
                #pragma unroll
                for (int j = 0; j < 4; ++j) {
                    acc1[i][j] += a[i] * b1[j];
                    acc2[i][j] += a[i] * b2[j];
                }
        }
        __syncthreads();
    }
    const float c0 = 0.7978845608028654f, c1 = 0.044715f;
    #pragma unroll
    for (int i = 0; i < 4; ++i) {
        int m = m0 + ty * 4 + i;
        #pragma unroll
        for (int j = 0; j < 4; ++j) {
            int n = n0 + tx * 4 + j;
            float hv = acc1[i][j] * acc2[i][j];
            float g  = 0.5f * hv * (1.0f + tanhf(c0 * (hv + c1 * hv * hv * hv)));
            Hout[((size_t)e * CAP + m) * HH + n] = g;
        }
    }
}

// ---------------------------------------------------------------------------
// 5. GEMM2 (per expert): EO = H @ w3   M=512 K=2048 N=1024
// ---------------------------------------------------------------------------
__global__ __launch_bounds__(256) void gemm2_kernel(
    const float* __restrict__ Hin, const float* __restrict__ W3,
    float* __restrict__ EO)
{
    const int BM = 64, BN = 64, BK = 16;
    int e  = blockIdx.z;
    int n0 = blockIdx.x * BN;
    int m0 = blockIdx.y * BM;
    const float* A = Hin + (size_t)e * CAP * HH;
    const float* B = W3  + (size_t)e * HH * DD;

    __shared__ float As[BK][BM + 1];
    __shared__ float Bs[BK][BN];

    int tid = threadIdx.x;
    int tx = tid & 15, ty = tid >> 4;
    float acc[4][4] = {};

    for (int k0 = 0; k0 < HH; k0 += BK) {
        {
            int m  = tid >> 2;
            int kq = (tid & 3) * 4;
            float4 v = *(const float4*)(A + (size_t)(m0 + m) * HH + k0 + kq);
            As[kq + 0][m] = v.x; As[kq + 1][m] = v.y;
            As[kq + 2][m] = v.z; As[kq + 3][m] = v.w;
        }
        {
            int kr = tid >> 4;
            int nq = (tid & 15) * 4;
            *(float4*)&Bs[kr][nq] = *(const float4*)(B + (size_t)(k0 + kr) * DD + n0 + nq);
        }
        __syncthreads();
        #pragma unroll
        for (int kk = 0; kk < BK; ++kk) {
            float a[4], b[4];
            #pragma unroll
            for (int i = 0; i < 4; ++i) a[i] = As[kk][ty * 4 + i];
            #pragma unroll
            for (int j = 0; j < 4; ++j) b[j] = Bs[kk][tx * 4 + j];
            #pragma unroll
            for (int i = 0; i < 4; ++i)
                #pragma unroll
                for (int j = 0; j < 4; ++j) acc[i][j] += a[i] * b[j];
        }
        __syncthreads();
    }
    #pragma unroll
    for (int i = 0; i < 4; ++i) {
        int m = m0 + ty * 4 + i;
        #pragma unroll
        for (int j = 0; j < 4; ++j) {
            int n = n0 + tx * 4 + j;
            EO[((size_t)e * CAP + m) * DD + n] = acc[i][j];
        }
    }
}

// ---------------------------------------------------------------------------
// 6. Combine: out[t] = g0 * (kept0 ? EO[e0][p0] : x[t]) + g1 * (...)
// ---------------------------------------------------------------------------
__global__ __launch_bounds__(256) void combine_kernel(
    const float* __restrict__ x, const float* __restrict__ EO,
    const int4* __restrict__ meta, const float2* __restrict__ gates,
    float* __restrict__ out)
{
    int t = blockIdx.x;
    int d = threadIdx.x * 4;
    int4  m = meta[t];
    float2 g = gates[t];
    float4 xv = *(const float4*)(x + (size_t)t * DD + d);
    float4 v0 = (m.y >= 0) ? *(const float4*)(EO + ((size_t)m.x * CAP + m.y) * DD + d) : xv;
    float4 v1 = (m.w >= 0) ? *(const float4*)(EO + ((size_t)m.z * CAP + m.w) * DD + d) : xv;
    float4 r;
    r.x = g.x * v0.x + g.y * v1.x;
    r.y = g.x * v0.y + g.y * v1.y;
    r.z = g.x * v0.z + g.y * v1.z;
    r.w = g.x * v0.w + g.y * v1.w;
    *(float4*)(out + (size_t)t * DD + d) = r;
}

// ---------------------------------------------------------------------------
extern "C" void kernel_launch(void* const* d_in, const int* in_sizes, int n_in,
                              void* d_out, int out_size, void* d_ws, size_t ws_size,
                              hipStream_t stream)
{
    const float* x  = (const float*)d_in[0];
    const float* rw = (const float*)d_in[1];
    const float* rb = (const float*)d_in[2];
    const float* w1 = (const float*)d_in[3];
    const float* w2 = (const float*)d_in[4];
    const float* w3 = (const float*)d_in[5];
    float* out = (float*)d_out;

    char* ws = (char*)d_ws;
    size_t off = 0;
    auto alloc = [&](size_t bytes) { char* p = ws + off; off = (off + bytes + 255) & ~(size_t)255; return p; };

    int2*   assign   = (int2*)  alloc(BT * sizeof(int2));
    float2* gates    = (float2*)alloc(BT * sizeof(float2));
    int4*   meta     = (int4*)  alloc(BT * sizeof(int4));
    int2*   slot_tok = (int2*)  alloc(EE * CAP * sizeof(int2));
    float*  grouped  = (float*) alloc((size_t)EE * CAP * DD * sizeof(float));
    float*  Hbuf     = (float*) alloc((size_t)EE * CAP * HH * sizeof(float));
    float*  eo       = (float*) alloc((size_t)EE * CAP * DD * sizeof(float));
    (void)ws_size;

    router_kernel<<<BT, 256, 0, stream>>>(x, rw, rb, assign, gates);
    scan_kernel<<<1, 64, 0, stream>>>(assign, meta, slot_tok);
    gather_kernel<<<EE * CAP, 256, 0, stream>>>(x, slot_tok, grouped);
    gemm1_kernel<<<dim3(HH / 64, CAP / 64, EE), 256, 0, stream>>>(grouped, w1, w2, Hbuf);
    gemm2_kernel<<<dim3(DD / 64, CAP / 64, EE), 256, 0, stream>>>(Hbuf, w3, eo);
    combine_kernel<<<BT, 256, 0, stream>>>(x, eo, meta, gates, out);
}

// Round 2
// 180.916 us; speedup vs baseline: 4.0856x; 4.0856x over previous
//
#include <hip/hip_runtime.h>
#include <hip/hip_bf16.h>
#include <math.h>

// Problem constants
#define BT   2048      // B*T tokens
#define DD   1024      // model dim
#define HH   2048      // hidden dim
#define EE   8         // experts
#define CAP  512       // expert capacity = floor(BT*0.25)

typedef unsigned short u16;
typedef unsigned int   u32;
typedef short bf16x8 __attribute__((ext_vector_type(8)));   // 8 bf16 (4 VGPRs) MFMA frag
typedef float f32x4  __attribute__((ext_vector_type(4)));   // MFMA accumulator
typedef u16   u16x4  __attribute__((ext_vector_type(4)));
typedef u16   u16x8  __attribute__((ext_vector_type(8)));

#define AS1 __attribute__((address_space(1)))
#define AS3 __attribute__((address_space(3)))

__device__ __forceinline__ u16 f2bf(float f) {   // RNE fp32->bf16
    union { float f; u32 u; } v; v.f = f;
    return (u16)((v.u + 0x7fffu + ((v.u >> 16) & 1u)) >> 16);
}
__device__ __forceinline__ float bf2f(u16 b) {   // exact bf16->fp32
    union { u32 u; float f; } v; v.u = ((u32)b) << 16;
    return v.f;
}

// ---------------------------------------------------------------------------
// 1. Router (fp32, exact): scores = x @ rw + rb ; top-2 ; softmax gates
// ---------------------------------------------------------------------------
__global__ __launch_bounds__(256) void router_kernel(
    const float* __restrict__ x, const float* __restrict__ rw,
    const float* __restrict__ rb, int2* __restrict__ assign,
    float2* __restrict__ gates)
{
    int t   = blockIdx.x;
    int tid = threadIdx.x;
    const float* xr = x + (size_t)t * DD;

    float p[EE];
    #pragma unroll
    for (int e = 0; e < EE; ++e) p[e] = 0.f;

    for (int d = tid; d < DD; d += 256) {
        float xv = xr[d];
        const float4* wr = (const float4*)(rw + (size_t)d * EE);
        float4 w0 = wr[0], w1 = wr[1];
        p[0] += xv * w0.x; p[1] += xv * w0.y; p[2] += xv * w0.z; p[3] += xv * w0.w;
        p[4] += xv * w1.x; p[5] += xv * w1.y; p[6] += xv * w1.z; p[7] += xv * w1.w;
    }
    #pragma unroll
    for (int off = 32; off; off >>= 1) {
        #pragma unroll
        for (int e = 0; e < EE; ++e) p[e] += __shfl_down(p[e], off);
    }
    __shared__ float red[4][EE];
    int wv = tid >> 6, ln = tid & 63;
    if (ln == 0) {
        #pragma unroll
        for (int e = 0; e < EE; ++e) red[wv][e] = p[e];
    }
    __syncthreads();
    if (tid == 0) {
        float s[EE];
        #pragma unroll
        for (int e = 0; e < EE; ++e)
            s[e] = red[0][e] + red[1][e] + red[2][e] + red[3][e] + rb[e];
        int i0 = 0;
        #pragma unroll
        for (int e = 1; e < EE; ++e) if (s[e] > s[i0]) i0 = e;
        int i1 = -1;
        #pragma unroll
        for (int e = 0; e < EE; ++e) {
            if (e == i0) continue;
            if (i1 < 0 || s[e] > s[i1]) i1 = e;
        }
        float e1 = expf(s[i1] - s[i0]);
        float denom = 1.0f + e1;
        assign[t] = make_int2(i0, i1);
        gates[t]  = make_float2(1.0f / denom, e1 / denom);
    }
}

// ---------------------------------------------------------------------------
// 2. Scan (unchanged from round 1 — verified exact cumsum semantics)
// ---------------------------------------------------------------------------
__global__ __launch_bounds__(64) void scan_kernel(
    const int2* __restrict__ assign, int4* __restrict__ meta,
    int2* __restrict__ slot_tok)
{
    __shared__ int c0[64][EE];
    __shared__ int cA[64][EE];
    int l = threadIdx.x;

    for (int i = l; i < EE * CAP; i += 64) slot_tok[i] = make_int2(-1, -1);
    #pragma unroll
    for (int e = 0; e < EE; ++e) { c0[l][e] = 0; cA[l][e] = 0; }
    __syncthreads();

    const int CH = BT / 64;
    int t0 = l * CH;

    for (int t = t0; t < t0 + CH; ++t) {
        int2 a = assign[t];
        c0[l][a.x]++; cA[l][a.x]++; cA[l][a.y]++;
    }
    __syncthreads();

    #pragma unroll
    for (int e = 0; e < EE; ++e) {
        int v = c0[l][e], inc = v;
        for (int d = 1; d < 64; d <<= 1) { int u = __shfl_up(inc, d); if (l >= d) inc += u; }
        c0[l][e] = inc - v;
        v = cA[l][e]; inc = v;
        for (int d = 1; d < 64; d <<= 1) { int u = __shfl_up(inc, d); if (l >= d) inc += u; }
        cA[l][e] = inc - v;
    }
    __syncthreads();

    for (int t = t0; t < t0 + CH; ++t) {
        int2 a = assign[t];
        int p0 = ++c0[l][a.x];  cA[l][a.x]++;
        int p1 = ++cA[l][a.y];
        int4 m;
        m.x = a.x; m.y = (p0 < CAP) ? p0 : -1;
        m.z = a.y; m.w = (p1 < CAP) ? p1 : -1;
        meta[t] = m;
        int* st = (int*)slot_tok;
        if (p0 < CAP) st[(a.x * CAP + p0) * 2 + 0] = t;
        if (p1 < CAP) st[(a.y * CAP + p1) * 2 + 1] = t;
    }
}

// ---------------------------------------------------------------------------
// 3. Gather -> bf16 grouped (E, CAP, DD)
// ---------------------------------------------------------------------------
__global__ __launch_bounds__(256) void gather_bf16(
    const float* __restrict__ x, const int2* __restrict__ slot_tok,
    u16* __restrict__ G)
{
    int es = blockIdx.x;
    int d  = threadIdx.x * 4;
    int2 st = slot_tok[es];
    float4 r = make_float4(0.f, 0.f, 0.f, 0.f);
    if (st.x >= 0) r = *(const float4*)(x + (size_t)st.x * DD + d);
    if (st.y >= 0) {
        float4 v = *(const float4*)(x + (size_t)st.y * DD + d);
        r.x += v.x; r.y += v.y; r.z += v.z; r.w += v.w;
    }
    u16x4 o;
    o[0] = f2bf(r.x); o[1] = f2bf(r.y); o[2] = f2bf(r.z); o[3] = f2bf(r.w);
    *(u16x4*)(G + (size_t)es * DD + d) = o;
}

// ---------------------------------------------------------------------------
// 4. Transpose+convert: src (E,R,C) fp32 -> dst (E,C,R) bf16. 64x64 LDS tiles.
// ---------------------------------------------------------------------------
__global__ __launch_bounds__(256) void transpose_k(
    const float* __restrict__ src, u16* __restrict__ dst, int R, int C)
{
    __shared__ u16 T[64][66];
    const int e  = blockIdx.z;
    const int c0 = blockIdx.x * 64;
    const int r0 = blockIdx.y * 64;
    const float* s = src + (size_t)e * R * C;
    u16* d = dst + (size_t)e * R * C;
    const int t = threadIdx.x;
    {
        const int rr = t >> 2, cq = (t & 3) * 16;
        const float* sp = s + (size_t)(r0 + rr) * C + c0 + cq;
        #pragma unroll
        for (int j = 0; j < 4; ++j) {
            float4 v = *(const float4*)(sp + j * 4);
            T[rr][cq + j*4 + 0] = f2bf(v.x);
            T[rr][cq + j*4 + 1] = f2bf(v.y);
            T[rr][cq + j*4 + 2] = f2bf(v.z);
            T[rr][cq + j*4 + 3] = f2bf(v.w);
        }
    }
    __syncthreads();
    {
        const int cc = t >> 2, rq = (t & 3) * 16;
        u16x8 lo, hi;
        #pragma unroll
        for (int j = 0; j < 8; ++j) { lo[j] = T[rq + j][cc]; hi[j] = T[rq + 8 + j][cc]; }
        u16* dp = d + (size_t)(c0 + cc) * R + r0 + rq;
        *(u16x8*)dp       = lo;
        *(u16x8*)(dp + 8) = hi;
    }
}

// ---------------------------------------------------------------------------
// 5. GEMM1 (MFMA): H = gelu((G@w1t^T)*(G@w2t^T)) ; tiles 128x128, BK=32
//    A = grouped bf16 (CAP,DD); B1t/B2t = (HH rows, DD k-contig) bf16
// ---------------------------------------------------------------------------
__global__ __launch_bounds__(256, 2) void gemm1_mfma(
    const u16* __restrict__ G, const u16* __restrict__ B1t,
    const u16* __restrict__ B2t, u16* __restrict__ H)
{
    __shared__ u16 As [128 * 32];
    __shared__ u16 B1s[128 * 32];
    __shared__ u16 B2s[128 * 32];

    const int e  = blockIdx.z;
    const int n0 = blockIdx.x * 128;
    const int m0 = blockIdx.y * 128;
    const int tid  = threadIdx.x;
    const int lane = tid & 63;
    const int w    = tid >> 6;
    const int wr = w >> 1, wc = w & 1;
    const int lr = lane & 15, lq = lane >> 4;

    const char* Ab  = (const char*)(G   + (size_t)e * CAP * DD + (size_t)m0 * DD);
    const char* B1b = (const char*)(B1t + (size_t)e * HH  * DD + (size_t)n0 * DD);
    const char* B2b = (const char*)(B2t + (size_t)e * HH  * DD + (size_t)n0 * DD);

    const int srow = lane >> 2;          // row-in-chunk
    const int skb  = (lane & 3) * 16;    // k byte offset

    f32x4 acc1[4][4] = {};
    f32x4 acc2[4][4] = {};

    for (int k0 = 0; k0 < DD; k0 += 32) {
        const size_t kbyte = (size_t)k0 * 2 + skb;
        #pragma unroll
        for (int c2 = 0; c2 < 2; ++c2) {
            const int c = 2 * w + c2;                       // chunk 0..7
            const size_t rb = (size_t)(c * 16 + srow) * (DD * 2) + kbyte;
            __builtin_amdgcn_global_load_lds((const AS1 void*)(Ab  + rb),
                (AS3 void*)((char*)As  + c * 1024), 16, 0, 0);
            __builtin_amdgcn_global_load_lds((const AS1 void*)(B1b + rb),
                (AS3 void*)((char*)B1s + c * 1024), 16, 0, 0);
            __builtin_amdgcn_global_load_lds((const AS1 void*)(B2b + rb),
                (AS3 void*)((char*)B2s + c * 1024), 16, 0, 0);
        }
        __syncthreads();
        bf16x8 av[4], b1v[4], b2v[4];
        #pragma unroll
        for (int m = 0; m < 4; ++m)
            av[m] = *(const bf16x8*)((const char*)As + (wr*64 + m*16 + lr) * 64 + lq * 16);
        #pragma unroll
        for (int n = 0; n < 4; ++n) {
            b1v[n] = *(const bf16x8*)((const char*)B1s + (wc*64 + n*16 + lr) * 64 + lq * 16);
            b2v[n] = *(const bf16x8*)((const char*)B2s + (wc*64 + n*16 + lr) * 64 + lq * 16);
        }
        #pragma unroll
        for (int m = 0; m < 4; ++m)
            #pragma unroll
            for (int n = 0; n < 4; ++n) {
                acc1[m][n] = __builtin_amdgcn_mfma_f32_16x16x32_bf16(av[m], b1v[n], acc1[m][n], 0, 0, 0);
                acc2[m][n] = __builtin_amdgcn_mfma_f32_16x16x32_bf16(av[m], b2v[n], acc2[m][n], 0, 0, 0);
            }
        __syncthreads();
    }

    u16* He = H + (size_t)e * CAP * HH;
    const int r0 = m0 + wr * 64 + lq * 4;
    const int c0 = n0 + wc * 64 + lr;
    const float gc0 = 0.7978845608028654f, gc1 = 0.044715f;
    #pragma unroll
    for (int m = 0; m < 4; ++m)
        #pragma unroll
        for (int n = 0; n < 4; ++n)
            #pragma unroll
            for (int r = 0; r < 4; ++r) {
                float hv = acc1[m][n][r] * acc2[m][n][r];
                float u  = gc0 * (hv + gc1 * hv * hv * hv);
                float th = 1.f - 2.f / (__expf(2.f * u) + 1.f);   // tanh(u)
                He[(size_t)(r0 + m*16 + r) * HH + (c0 + n*16)] = f2bf(0.5f * hv * (1.f + th));
            }
}

// ---------------------------------------------------------------------------
// 6. GEMM2 (MFMA): EO = H @ w3 ; A = H bf16 (CAP,HH); B = w3t (DD rows, HH k)
// ---------------------------------------------------------------------------
__global__ __launch_bounds__(256, 2) void gemm2_mfma(
    const u16* __restrict__ Hin, const u16* __restrict__ B3t, u16* __restrict__ EO)
{
    __shared__ u16 As[128 * 32];
    __shared__ u16 Bs[128 * 32];

    const int e  = blockIdx.z;
    const int n0 = blockIdx.x * 128;
    const int m0 = blockIdx.y * 128;
    const int tid  = threadIdx.x;
    const int lane = tid & 63;
    const int w    = tid >> 6;
    const int wr = w >> 1, wc = w & 1;
    const int lr = lane & 15, lq = lane >> 4;

    const char* Ab = (const char*)(Hin + (size_t)e * CAP * HH + (size_t)m0 * HH);
    const char* Bb = (const char*)(B3t + (size_t)e * DD  * HH + (size_t)n0 * HH);

    const int srow = lane >> 2;
    const int skb  = (lane & 3) * 16;

    f32x4 acc[4][4] = {};

    for (int k0 = 0; k0 < HH; k0 += 32) {
        const size_t kbyte = (size_t)k0 * 2 + skb;
        #pragma unroll
        for (int c2 = 0; c2 < 2; ++c2) {
            const int c = 2 * w + c2;
            const size_t rb = (size_t)(c * 16 + srow) * (HH * 2) + kbyte;
            __builtin_amdgcn_global_load_lds((const AS1 void*)(Ab + rb),
                (AS3 void*)((char*)As + c * 1024), 16, 0, 0);
            __builtin_amdgcn_global_load_lds((const AS1 void*)(Bb + rb),
                (AS3 void*)((char*)Bs + c * 1024), 16, 0, 0);
        }
        __syncthreads();
        bf16x8 av[4], bv[4];
        #pragma unroll
        for (int m = 0; m < 4; ++m)
            av[m] = *(const bf16x8*)((const char*)As + (wr*64 + m*16 + lr) * 64 + lq * 16);
        #pragma unroll
        for (int n = 0; n < 4; ++n)
            bv[n] = *(const bf16x8*)((const char*)Bs + (wc*64 + n*16 + lr) * 64 + lq * 16);
        #pragma unroll
        for (int m = 0; m < 4; ++m)
            #pragma unroll
            for (int n = 0; n < 4; ++n)
                acc[m][n] = __builtin_amdgcn_mfma_f32_16x16x32_bf16(av[m], bv[n], acc[m][n], 0, 0, 0);
        __syncthreads();
    }

    u16* Oe = EO + (size_t)e * CAP * DD;
    const int r0 = m0 + wr * 64 + lq * 4;
    const int c0 = n0 + wc * 64 + lr;
    #pragma unroll
    for (int m = 0; m < 4; ++m)
        #pragma unroll
        for (int n = 0; n < 4; ++n)
            #pragma unroll
            for (int r = 0; r < 4; ++r)
                Oe[(size_t)(r0 + m*16 + r) * DD + (c0 + n*16)] = f2bf(acc[m][n][r]);
}

// ---------------------------------------------------------------------------
// 7. Combine: out[t] = g0*(kept0 ? EO[e0][p0] : x) + g1*(...)   (EO is bf16)
// ---------------------------------------------------------------------------
__global__ __launch_bounds__(256) void combine_kernel(
    const float* __restrict__ x, const u16* __restrict__ EO,
    const int4* __restrict__ meta, const float2* __restrict__ gates,
    float* __restrict__ out)
{
    int t = blockIdx.x;
    int d = threadIdx.x * 4;
    int4  m = meta[t];
    float2 g = gates[t];
    float4 xv = *(const float4*)(x + (size_t)t * DD + d);
    float4 v0 = xv, v1 = xv;
    if (m.y >= 0) {
        u16x4 q = *(const u16x4*)(EO + ((size_t)m.x * CAP + m.y) * DD + d);
        v0 = make_float4(bf2f(q[0]), bf2f(q[1]), bf2f(q[2]), bf2f(q[3]));
    }
    if (m.w >= 0) {
        u16x4 q = *(const u16x4*)(EO + ((size_t)m.z * CAP + m.w) * DD + d);
        v1 = make_float4(bf2f(q[0]), bf2f(q[1]), bf2f(q[2]), bf2f(q[3]));
    }
    float4 r;
    r.x = g.x * v0.x + g.y * v1.x;
    r.y = g.x * v0.y + g.y * v1.y;
    r.z = g.x * v0.z + g.y * v1.z;
    r.w = g.x * v0.w + g.y * v1.w;
    *(float4*)(out + (size_t)t * DD + d) = r;
}

// ---------------------------------------------------------------------------
extern "C" void kernel_launch(void* const* d_in, const int* in_sizes, int n_in,
                              void* d_out, int out_size, void* d_ws, size_t ws_size,
                              hipStream_t stream)
{
    const float* x  = (const float*)d_in[0];
    const float* rw = (const float*)d_in[1];
    const float* rb = (const float*)d_in[2];
    const float* w1 = (const float*)d_in[3];
    const float* w2 = (const float*)d_in[4];
    const float* w3 = (const float*)d_in[5];
    float* out = (float*)d_out;

    char* ws = (char*)d_ws;
    size_t off = 0;
    auto alloc = [&](size_t bytes) { char* p = ws + off; off = (off + bytes + 255) & ~(size_t)255; return p; };

    int2*   assign   = (int2*)  alloc(BT * sizeof(int2));
    float2* gates    = (float2*)alloc(BT * sizeof(float2));
    int4*   meta     = (int4*)  alloc(BT * sizeof(int4));
    int2*   slot_tok = (int2*)  alloc(EE * CAP * sizeof(int2));
    u16*    grouped  = (u16*)   alloc((size_t)EE * CAP * DD * 2);   //  8.4 MB
    u16*    Hbuf     = (u16*)   alloc((size_t)EE * CAP * HH * 2);   // 16.8 MB
    u16*    eo       = (u16*)   alloc((size_t)EE * CAP * DD * 2);   //  8.4 MB
    u16*    w1t      = (u16*)   alloc((size_t)EE * DD * HH * 2);    // 33.6 MB
    u16*    w2t      = (u16*)   alloc((size_t)EE * DD * HH * 2);    // 33.6 MB
    u16*    w3t      = w1t;   // w3t needed only after gemm1 — alias w1t
    (void)ws_size;

    // weight transposes (fp32 -> bf16, K-contiguous rows for MFMA B-frags)
    transpose_k<<<dim3(HH / 64, DD / 64, EE), 256, 0, stream>>>(w1, w1t, DD, HH);
    transpose_k<<<dim3(HH / 64, DD / 64, EE), 256, 0, stream>>>(w2, w2t, DD, HH);

    router_kernel<<<BT, 256, 0, stream>>>(x, rw, rb, assign, gates);
    scan_kernel<<<1, 64, 0, stream>>>(assign, meta, slot_tok);
    gather_bf16<<<EE * CAP, 256, 0, stream>>>(x, slot_tok, grouped);

    gemm1_mfma<<<dim3(HH / 128, CAP / 128, EE), 256, 0, stream>>>(grouped, w1t, w2t, Hbuf);

    transpose_k<<<dim3(DD / 64, HH / 64, EE), 256, 0, stream>>>(w3, w3t, HH, DD);

    gemm2_mfma<<<dim3(DD / 128, CAP / 128, EE), 256, 0, stream>>>(Hbuf, w3t, eo);

    combine_kernel<<<BT, 256, 0, stream>>>(x, eo, meta, gates, out);
}

// Round 4
// 172.878 us; speedup vs baseline: 4.2756x; 1.0465x over previous
//
#include <hip/hip_runtime.h>
#include <hip/hip_bf16.h>
#include <math.h>

// Problem constants
#define BT   2048      // B*T tokens
#define DD   1024      // model dim
#define HH   2048      // hidden dim
#define EE   8         // experts
#define CAP  512       // expert capacity = floor(BT*0.25)

typedef unsigned short u16;
typedef unsigned int   u32;
typedef short bf16x8 __attribute__((ext_vector_type(8)));   // 8 bf16 (4 VGPRs) MFMA frag
typedef float f32x4  __attribute__((ext_vector_type(4)));   // MFMA accumulator
typedef u16   u16x4  __attribute__((ext_vector_type(4)));
typedef u16   u16x8  __attribute__((ext_vector_type(8)));

#define AS1 __attribute__((address_space(1)))
#define AS3 __attribute__((address_space(3)))

__device__ __forceinline__ u16 f2bf(float f) {   // RNE fp32->bf16
    union { float f; u32 u; } v; v.f = f;
    return (u16)((v.u + 0x7fffu + ((v.u >> 16) & 1u)) >> 16);
}
__device__ __forceinline__ float bf2f(u16 b) {   // exact bf16->fp32
    union { u32 u; float f; } v; v.u = ((u32)b) << 16;
    return v.f;
}

// ---------------------------------------------------------------------------
// 1. Router (fp32, exact): scores = x @ rw + rb ; top-2 ; softmax gates
// ---------------------------------------------------------------------------
__global__ __launch_bounds__(256) void router_kernel(
    const float* __restrict__ x, const float* __restrict__ rw,
    const float* __restrict__ rb, int2* __restrict__ assign,
    float2* __restrict__ gates)
{
    int t   = blockIdx.x;
    int tid = threadIdx.x;
    const float* xr = x + (size_t)t * DD;

    float p[EE];
    #pragma unroll
    for (int e = 0; e < EE; ++e) p[e] = 0.f;

    for (int d = tid; d < DD; d += 256) {
        float xv = xr[d];
        const float4* wr = (const float4*)(rw + (size_t)d * EE);
        float4 w0 = wr[0], w1 = wr[1];
        p[0] += xv * w0.x; p[1] += xv * w0.y; p[2] += xv * w0.z; p[3] += xv * w0.w;
        p[4] += xv * w1.x; p[5] += xv * w1.y; p[6] += xv * w1.z; p[7] += xv * w1.w;
    }
    #pragma unroll
    for (int off = 32; off; off >>= 1) {
        #pragma unroll
        for (int e = 0; e < EE; ++e) p[e] += __shfl_down(p[e], off);
    }
    __shared__ float red[4][EE];
    int wv = tid >> 6, ln = tid & 63;
    if (ln == 0) {
        #pragma unroll
        for (int e = 0; e < EE; ++e) red[wv][e] = p[e];
    }
    __syncthreads();
    if (tid == 0) {
        float s[EE];
        #pragma unroll
        for (int e = 0; e < EE; ++e)
            s[e] = red[0][e] + red[1][e] + red[2][e] + red[3][e] + rb[e];
        int i0 = 0;
        #pragma unroll
        for (int e = 1; e < EE; ++e) if (s[e] > s[i0]) i0 = e;
        int i1 = -1;
        #pragma unroll
        for (int e = 0; e < EE; ++e) {
            if (e == i0) continue;
            if (i1 < 0 || s[e] > s[i1]) i1 = e;
        }
        float e1 = expf(s[i1] - s[i0]);
        float denom = 1.0f + e1;
        assign[t] = make_int2(i0, i1);
        gates[t]  = make_float2(1.0f / denom, e1 / denom);
    }
}

// ---------------------------------------------------------------------------
// 2. Scan (exact reference cumsum semantics — verified round 1)
// ---------------------------------------------------------------------------
__global__ __launch_bounds__(64) void scan_kernel(
    const int2* __restrict__ assign, int4* __restrict__ meta,
    int2* __restrict__ slot_tok)
{
    __shared__ int c0[64][EE];
    __shared__ int cA[64][EE];
    int l = threadIdx.x;

    for (int i = l; i < EE * CAP; i += 64) slot_tok[i] = make_int2(-1, -1);
    #pragma unroll
    for (int e = 0; e < EE; ++e) { c0[l][e] = 0; cA[l][e] = 0; }
    __syncthreads();

    const int CH = BT / 64;
    int t0 = l * CH;

    for (int t = t0; t < t0 + CH; ++t) {
        int2 a = assign[t];
        c0[l][a.x]++; cA[l][a.x]++; cA[l][a.y]++;
    }
    __syncthreads();

    #pragma unroll
    for (int e = 0; e < EE; ++e) {
        int v = c0[l][e], inc = v;
        for (int d = 1; d < 64; d <<= 1) { int u = __shfl_up(inc, d); if (l >= d) inc += u; }
        c0[l][e] = inc - v;
        v = cA[l][e]; inc = v;
        for (int d = 1; d < 64; d <<= 1) { int u = __shfl_up(inc, d); if (l >= d) inc += u; }
        cA[l][e] = inc - v;
    }
    __syncthreads();

    for (int t = t0; t < t0 + CH; ++t) {
        int2 a = assign[t];
        int p0 = ++c0[l][a.x];  cA[l][a.x]++;
        int p1 = ++cA[l][a.y];
        int4 m;
        m.x = a.x; m.y = (p0 < CAP) ? p0 : -1;
        m.z = a.y; m.w = (p1 < CAP) ? p1 : -1;
        meta[t] = m;
        int* st = (int*)slot_tok;
        if (p0 < CAP) st[(a.x * CAP + p0) * 2 + 0] = t;
        if (p1 < CAP) st[(a.y * CAP + p1) * 2 + 1] = t;
    }
}

// ---------------------------------------------------------------------------
// 3. Gather -> bf16 grouped (E, CAP, DD)
// ---------------------------------------------------------------------------
__global__ __launch_bounds__(256) void gather_bf16(
    const float* __restrict__ x, const int2* __restrict__ slot_tok,
    u16* __restrict__ G)
{
    int es = blockIdx.x;
    int d  = threadIdx.x * 4;
    int2 st = slot_tok[es];
    float4 r = make_float4(0.f, 0.f, 0.f, 0.f);
    if (st.x >= 0) r = *(const float4*)(x + (size_t)st.x * DD + d);
    if (st.y >= 0) {
        float4 v = *(const float4*)(x + (size_t)st.y * DD + d);
        r.x += v.x; r.y += v.y; r.z += v.z; r.w += v.w;
    }
    u16x4 o;
    o[0] = f2bf(r.x); o[1] = f2bf(r.y); o[2] = f2bf(r.z); o[3] = f2bf(r.w);
    *(u16x4*)(G + (size_t)es * DD + d) = o;
}

// ---------------------------------------------------------------------------
// 4. Transpose+convert: src (E,R,C) fp32 -> dst (E,C,R) bf16. 64x64 LDS tiles.
//    dual-source variant: z in [0, 2E) selects w1 (z<E) or w2.
// ---------------------------------------------------------------------------
__global__ __launch_bounds__(256) void transpose12_k(
    const float* __restrict__ srcA, const float* __restrict__ srcB,
    u16* __restrict__ dstA, u16* __restrict__ dstB)
{
    const int R = DD, C = HH;
    __shared__ u16 T[64][66];
    const int z  = blockIdx.z;
    const int e  = (z < EE) ? z : z - EE;
    const float* s = ((z < EE) ? srcA : srcB) + (size_t)e * R * C;
    u16*         d = ((z < EE) ? dstA : dstB) + (size_t)e * R * C;
    const int c0 = blockIdx.x * 64;
    const int r0 = blockIdx.y * 64;
    const int t = threadIdx.x;
    {
        const int rr = t >> 2, cq = (t & 3) * 16;
        const float* sp = s + (size_t)(r0 + rr) * C + c0 + cq;
        #pragma unroll
        for (int j = 0; j < 4; ++j) {
            float4 v = *(const float4*)(sp + j * 4);
            T[rr][cq + j*4 + 0] = f2bf(v.x);
            T[rr][cq + j*4 + 1] = f2bf(v.y);
            T[rr][cq + j*4 + 2] = f2bf(v.z);
            T[rr][cq + j*4 + 3] = f2bf(v.w);
        }
    }
    __syncthreads();
    {
        const int cc = t >> 2, rq = (t & 3) * 16;
        u16x8 lo, hi;
        #pragma unroll
        for (int j = 0; j < 8; ++j) { lo[j] = T[rq + j][cc]; hi[j] = T[rq + 8 + j][cc]; }
        u16* dp = d + (size_t)(c0 + cc) * R + r0 + rq;
        *(u16x8*)dp       = lo;
        *(u16x8*)(dp + 8) = hi;
    }
}

__global__ __launch_bounds__(256) void transpose_k(
    const float* __restrict__ src, u16* __restrict__ dst, int R, int C)
{
    __shared__ u16 T[64][66];
    const int e  = blockIdx.z;
    const int c0 = blockIdx.x * 64;
    const int r0 = blockIdx.y * 64;
    const float* s = src + (size_t)e * R * C;
    u16* d = dst + (size_t)e * R * C;
    const int t = threadIdx.x;
    {
        const int rr = t >> 2, cq = (t & 3) * 16;
        const float* sp = s + (size_t)(r0 + rr) * C + c0 + cq;
        #pragma unroll
        for (int j = 0; j < 4; ++j) {
            float4 v = *(const float4*)(sp + j * 4);
            T[rr][cq + j*4 + 0] = f2bf(v.x);
            T[rr][cq + j*4 + 1] = f2bf(v.y);
            T[rr][cq + j*4 + 2] = f2bf(v.z);
            T[rr][cq + j*4 + 3] = f2bf(v.w);
        }
    }
    __syncthreads();
    {
        const int cc = t >> 2, rq = (t & 3) * 16;
        u16x8 lo, hi;
        #pragma unroll
        for (int j = 0; j < 8; ++j) { lo[j] = T[rq + j][cc]; hi[j] = T[rq + 8 + j][cc]; }
        u16* dp = d + (size_t)(c0 + cc) * R + r0 + rq;
        *(u16x8*)dp       = lo;
        *(u16x8*)(dp + 8) = hi;
    }
}

// ---------------------------------------------------------------------------
// LDS XOR-swizzle (T2, rule #21: linear global_load_lds dest + pre-swizzled
// global SOURCE + swizzled READ).  Chunk row = 64 B = 4 x 16B slots.
// Data slot s_data for row r lives at LDS slot s_data ^ ((r>>1)&3):
// each ds_read_b128 quarter-wave then spreads over all 8 bankspace slots
// (2 lanes each -> conflict-free; was 8-way).
// ---------------------------------------------------------------------------

// ---------------------------------------------------------------------------
// 5. GEMM1 (MFMA): H = gelu((G@w1t^T)*(G@w2t^T)) ; tiles 128x128, BK=32
// ---------------------------------------------------------------------------
__global__ __launch_bounds__(256, 2) void gemm1_mfma(
    const u16* __restrict__ G, const u16* __restrict__ B1t,
    const u16* __restrict__ B2t, u16* __restrict__ H)
{
    __shared__ u16 As [128 * 32];
    __shared__ u16 B1s[128 * 32];
    __shared__ u16 B2s[128 * 32];

    const int e  = blockIdx.z;
    const int n0 = blockIdx.x * 128;
    const int m0 = blockIdx.y * 128;
    const int tid  = threadIdx.x;
    const int lane = tid & 63;
    const int w    = tid >> 6;
    const int wr = w >> 1, wc = w & 1;
    const int lr = lane & 15, lq = lane >> 4;

    const char* Ab  = (const char*)(G   + (size_t)e * CAP * DD + (size_t)m0 * DD);
    const char* B1b = (const char*)(B1t + (size_t)e * HH  * DD + (size_t)n0 * DD);
    const char* B2b = (const char*)(B2t + (size_t)e * HH  * DD + (size_t)n0 * DD);

    const int srow = lane >> 2;                                  // row in chunk
    const int skb  = ((lane & 3) ^ ((lane >> 3) & 3)) * 16;      // pre-swizzled k-slot

    f32x4 acc1[4][4] = {};
    f32x4 acc2[4][4] = {};

    for (int k0 = 0; k0 < DD; k0 += 32) {
        const size_t kbyte = (size_t)k0 * 2 + skb;
        #pragma unroll
        for (int c2 = 0; c2 < 2; ++c2) {
            const int c = 2 * w + c2;                       // chunk 0..7
            const size_t rb = (size_t)(c * 16 + srow) * (DD * 2) + kbyte;
            __builtin_amdgcn_global_load_lds((const AS1 void*)(Ab  + rb),
                (AS3 void*)((char*)As  + c * 1024), 16, 0, 0);
            __builtin_amdgcn_global_load_lds((const AS1 void*)(B1b + rb),
                (AS3 void*)((char*)B1s + c * 1024), 16, 0, 0);
            __builtin_amdgcn_global_load_lds((const AS1 void*)(B2b + rb),
                (AS3 void*)((char*)B2s + c * 1024), 16, 0, 0);
        }
        __syncthreads();
        bf16x8 av[4], b1v[4], b2v[4];
        #pragma unroll
        for (int m = 0; m < 4; ++m) {
            const int row = wr*64 + m*16 + lr;
            const int sl  = (lq ^ ((row >> 1) & 3)) * 16;
            av[m] = *(const bf16x8*)((const char*)As + row * 64 + sl);
        }
        #pragma unroll
        for (int n = 0; n < 4; ++n) {
            const int row = wc*64 + n*16 + lr;
            const int sl  = (lq ^ ((row >> 1) & 3)) * 16;
            b1v[n] = *(const bf16x8*)((const char*)B1s + row * 64 + sl);
            b2v[n] = *(const bf16x8*)((const char*)B2s + row * 64 + sl);
        }
        #pragma unroll
        for (int m = 0; m < 4; ++m)
            #pragma unroll
            for (int n = 0; n < 4; ++n) {
                acc1[m][n] = __builtin_amdgcn_mfma_f32_16x16x32_bf16(av[m], b1v[n], acc1[m][n], 0, 0, 0);
                acc2[m][n] = __builtin_amdgcn_mfma_f32_16x16x32_bf16(av[m], b2v[n], acc2[m][n], 0, 0, 0);
            }
        __syncthreads();
    }

    u16* He = H + (size_t)e * CAP * HH;
    const int r0 = m0 + wr * 64 + lq * 4;
    const int c0 = n0 + wc * 64 + lr;
    const float gc0 = 0.7978845608028654f, gc1 = 0.044715f;
    #pragma unroll
    for (int m = 0; m < 4; ++m)
        #pragma unroll
        for (int n = 0; n < 4; ++n)
            #pragma unroll
            for (int r = 0; r < 4; ++r) {
                float hv = acc1[m][n][r] * acc2[m][n][r];
                float u  = gc0 * (hv + gc1 * hv * hv * hv);
                float th = 1.f - 2.f / (__expf(2.f * u) + 1.f);   // tanh(u)
                He[(size_t)(r0 + m*16 + r) * HH + (c0 + n*16)] = f2bf(0.5f * hv * (1.f + th));
            }
}

// ---------------------------------------------------------------------------
// 6. GEMM2 (MFMA): EO = H @ w3 ; A = H bf16 (CAP,HH); B = w3t (DD rows, HH k)
// ---------------------------------------------------------------------------
__global__ __launch_bounds__(256, 2) void gemm2_mfma(
    const u16* __restrict__ Hin, const u16* __restrict__ B3t, u16* __restrict__ EO)
{
    __shared__ u16 As[128 * 32];
    __shared__ u16 Bs[128 * 32];

    const int e  = blockIdx.z;
    const int n0 = blockIdx.x * 128;
    const int m0 = blockIdx.y * 128;
    const int tid  = threadIdx.x;
    const int lane = tid & 63;
    const int w    = tid >> 6;
    const int wr = w >> 1, wc = w & 1;
    const int lr = lane & 15, lq = lane >> 4;

    const char* Ab = (const char*)(Hin + (size_t)e * CAP * HH + (size_t)m0 * HH);
    const char* Bb = (const char*)(B3t + (size_t)e * DD  * HH + (size_t)n0 * HH);

    const int srow = lane >> 2;
    const int skb  = ((lane & 3) ^ ((lane >> 3) & 3)) * 16;

    f32x4 acc[4][4] = {};

    for (int k0 = 0; k0 < HH; k0 += 32) {
        const size_t kbyte = (size_t)k0 * 2 + skb;
        #pragma unroll
        for (int c2 = 0; c2 < 2; ++c2) {
            const int c = 2 * w + c2;
            const size_t rb = (size_t)(c * 16 + srow) * (HH * 2) + kbyte;
            __builtin_amdgcn_global_load_lds((const AS1 void*)(Ab + rb),
                (AS3 void*)((char*)As + c * 1024), 16, 0, 0);
            __builtin_amdgcn_global_load_lds((const AS1 void*)(Bb + rb),
                (AS3 void*)((char*)Bs + c * 1024), 16, 0, 0);
        }
        __syncthreads();
        bf16x8 av[4], bv[4];
        #pragma unroll
        for (int m = 0; m < 4; ++m) {
            const int row = wr*64 + m*16 + lr;
            const int sl  = (lq ^ ((row >> 1) & 3)) * 16;
            av[m] = *(const bf16x8*)((const char*)As + row * 64 + sl);
        }
        #pragma unroll
        for (int n = 0; n < 4; ++n) {
            const int row = wc*64 + n*16 + lr;
            const int sl  = (lq ^ ((row >> 1) & 3)) * 16;
            bv[n] = *(const bf16x8*)((const char*)Bs + row * 64 + sl);
        }
        #pragma unroll
        for (int m = 0; m < 4; ++m)
            #pragma unroll
            for (int n = 0; n < 4; ++n)
                acc[m][n] = __builtin_amdgcn_mfma_f32_16x16x32_bf16(av[m], bv[n], acc[m][n], 0, 0, 0);
        __syncthreads();
    }

    u16* Oe = EO + (size_t)e * CAP * DD;
    const int r0 = m0 + wr * 64 + lq * 4;
    const int c0 = n0 + wc * 64 + lr;
    #pragma unroll
    for (int m = 0; m < 4; ++m)
        #pragma unroll
        for (int n = 0; n < 4; ++n)
            #pragma unroll
            for (int r = 0; r < 4; ++r)
                Oe[(size_t)(r0 + m*16 + r) * DD + (c0 + n*16)] = f2bf(acc[m][n][r]);
}

// ---------------------------------------------------------------------------
// 7. Combine: out[t] = g0*(kept0 ? EO[e0][p0] : x) + g1*(...)   (EO is bf16)
// ---------------------------------------------------------------------------
__global__ __launch_bounds__(256) void combine_kernel(
    const float* __restrict__ x, const u16* __restrict__ EO,
    const int4* __restrict__ meta, const float2* __restrict__ gates,
    float* __restrict__ out)
{
    int t = blockIdx.x;
    int d = threadIdx.x * 4;
    int4  m = meta[t];
    float2 g = gates[t];
    float4 xv = *(const float4*)(x + (size_t)t * DD + d);
    float4 v0 = xv, v1 = xv;
    if (m.y >= 0) {
        u16x4 q = *(const u16x4*)(EO + ((size_t)m.x * CAP + m.y) * DD + d);
        v0 = make_float4(bf2f(q[0]), bf2f(q[1]), bf2f(q[2]), bf2f(q[3]));
    }
    if (m.w >= 0) {
        u16x4 q = *(const u16x4*)(EO + ((size_t)m.z * CAP + m.w) * DD + d);
        v1 = make_float4(bf2f(q[0]), bf2f(q[1]), bf2f(q[2]), bf2f(q[3]));
    }
    float4 r;
    r.x = g.x * v0.x + g.y * v1.x;
    r.y = g.x * v0.y + g.y * v1.y;
    r.z = g.x * v0.z + g.y * v1.z;
    r.w = g.x * v0.w + g.y * v1.w;
    *(float4*)(out + (size_t)t * DD + d) = r;
}

// ---------------------------------------------------------------------------
extern "C" void kernel_launch(void* const* d_in, const int* in_sizes, int n_in,
                              void* d_out, int out_size, void* d_ws, size_t ws_size,
                              hipStream_t stream)
{
    const float* x  = (const float*)d_in[0];
    const float* rw = (const float*)d_in[1];
    const float* rb = (const float*)d_in[2];
    const float* w1 = (const float*)d_in[3];
    const float* w2 = (const float*)d_in[4];
    const float* w3 = (const float*)d_in[5];
    float* out = (float*)d_out;

    char* ws = (char*)d_ws;
    size_t off = 0;
    auto alloc = [&](size_t bytes) { char* p = ws + off; off = (off + bytes + 255) & ~(size_t)255; return p; };

    int2*   assign   = (int2*)  alloc(BT * sizeof(int2));
    float2* gates    = (float2*)alloc(BT * sizeof(float2));
    int4*   meta     = (int4*)  alloc(BT * sizeof(int4));
    int2*   slot_tok = (int2*)  alloc(EE * CAP * sizeof(int2));
    u16*    grouped  = (u16*)   alloc((size_t)EE * CAP * DD * 2);   //  8.4 MB
    u16*    Hbuf     = (u16*)   alloc((size_t)EE * CAP * HH * 2);   // 16.8 MB
    u16*    eo       = (u16*)   alloc((size_t)EE * CAP * DD * 2);   //  8.4 MB
    u16*    w1t      = (u16*)   alloc((size_t)EE * DD * HH * 2);    // 33.6 MB
    u16*    w2t      = (u16*)   alloc((size_t)EE * DD * HH * 2);    // 33.6 MB
    u16*    w3t      = w1t;   // w3t needed only after gemm1 — alias w1t
    (void)ws_size;

    // weight transposes (fp32 -> bf16, K-contiguous rows for MFMA B-frags)
    transpose12_k<<<dim3(HH / 64, DD / 64, 2 * EE), 256, 0, stream>>>(w1, w2, w1t, w2t);

    router_kernel<<<BT, 256, 0, stream>>>(x, rw, rb, assign, gates);
    scan_kernel<<<1, 64, 0, stream>>>(assign, meta, slot_tok);
    gather_bf16<<<EE * CAP, 256, 0, stream>>>(x, slot_tok, grouped);

    gemm1_mfma<<<dim3(HH / 128, CAP / 128, EE), 256, 0, stream>>>(grouped, w1t, w2t, Hbuf);

    transpose_k<<<dim3(DD / 64, HH / 64, EE), 256, 0, stream>>>(w3, w3t, HH, DD);

    gemm2_mfma<<<dim3(DD / 128, CAP / 128, EE), 256, 0, stream>>>(Hbuf, w3t, eo);

    combine_kernel<<<BT, 256, 0, stream>>>(x, eo, meta, gates, out);
}

// Round 5
// 172.435 us; speedup vs baseline: 4.2865x; 1.0026x over previous
//
#include <hip/hip_runtime.h>
#include <hip/hip_bf16.h>
#include <math.h>

// Problem constants
#define BT   2048      // B*T tokens
#define DD   1024      // model dim
#define HH   2048      // hidden dim
#define EE   8         // experts
#define CAP  512       // expert capacity = floor(BT*0.25)

typedef unsigned short u16;
typedef unsigned int   u32;
typedef short bf16x8 __attribute__((ext_vector_type(8)));   // 8 bf16 (4 VGPRs) MFMA frag
typedef float f32x4  __attribute__((ext_vector_type(4)));   // MFMA accumulator
typedef u16   u16x4  __attribute__((ext_vector_type(4)));
typedef u16   u16x8  __attribute__((ext_vector_type(8)));
typedef u32   u32x4  __attribute__((ext_vector_type(4)));

#define AS1 __attribute__((address_space(1)))
#define AS3 __attribute__((address_space(3)))

__device__ __forceinline__ u16 f2bf(float f) {   // RNE fp32->bf16
    union { float f; u32 u; } v; v.f = f;
    return (u16)((v.u + 0x7fffu + ((v.u >> 16) & 1u)) >> 16);
}
__device__ __forceinline__ float bf2f(u16 b) {   // exact bf16->fp32
    union { u32 u; float f; } v; v.u = ((u32)b) << 16;
    return v.f;
}
// pack two fp32 -> two bf16 in one u32 (RNE), gfx950 HW instr (no builtin)
__device__ __forceinline__ u32 pkbf(float lo, float hi) {
    u32 r;
    asm("v_cvt_pk_bf16_f32 %0, %1, %2" : "=v"(r) : "v"(lo), "v"(hi));
    return r;
}

// ---------------------------------------------------------------------------
// 1. Router (fp32, exact): scores = x @ rw + rb ; top-2 ; softmax gates
// ---------------------------------------------------------------------------
__global__ __launch_bounds__(256) void router_kernel(
    const float* __restrict__ x, const float* __restrict__ rw,
    const float* __restrict__ rb, int2* __restrict__ assign,
    float2* __restrict__ gates)
{
    int t   = blockIdx.x;
    int tid = threadIdx.x;
    const float* xr = x + (size_t)t * DD;

    float p[EE];
    #pragma unroll
    for (int e = 0; e < EE; ++e) p[e] = 0.f;

    for (int d = tid; d < DD; d += 256) {
        float xv = xr[d];
        const float4* wr = (const float4*)(rw + (size_t)d * EE);
        float4 w0 = wr[0], w1 = wr[1];
        p[0] += xv * w0.x; p[1] += xv * w0.y; p[2] += xv * w0.z; p[3] += xv * w0.w;
        p[4] += xv * w1.x; p[5] += xv * w1.y; p[6] += xv * w1.z; p[7] += xv * w1.w;
    }
    #pragma unroll
    for (int off = 32; off; off >>= 1) {
        #pragma unroll
        for (int e = 0; e < EE; ++e) p[e] += __shfl_down(p[e], off);
    }
    __shared__ float red[4][EE];
    int wv = tid >> 6, ln = tid & 63;
    if (ln == 0) {
        #pragma unroll
        for (int e = 0; e < EE; ++e) red[wv][e] = p[e];
    }
    __syncthreads();
    if (tid == 0) {
        float s[EE];
        #pragma unroll
        for (int e = 0; e < EE; ++e)
            s[e] = red[0][e] + red[1][e] + red[2][e] + red[3][e] + rb[e];
        int i0 = 0;
        #pragma unroll
        for (int e = 1; e < EE; ++e) if (s[e] > s[i0]) i0 = e;
        int i1 = -1;
        #pragma unroll
        for (int e = 0; e < EE; ++e) {
            if (e == i0) continue;
            if (i1 < 0 || s[e] > s[i1]) i1 = e;
        }
        float e1 = expf(s[i1] - s[i0]);
        float denom = 1.0f + e1;
        assign[t] = make_int2(i0, i1);
        gates[t]  = make_float2(1.0f / denom, e1 / denom);
    }
}

// ---------------------------------------------------------------------------
// 2. Scan (exact reference cumsum semantics — verified round 1)
// ---------------------------------------------------------------------------
__global__ __launch_bounds__(64) void scan_kernel(
    const int2* __restrict__ assign, int4* __restrict__ meta,
    int2* __restrict__ slot_tok)
{
    __shared__ int c0[64][EE];
    __shared__ int cA[64][EE];
    int l = threadIdx.x;

    for (int i = l; i < EE * CAP; i += 64) slot_tok[i] = make_int2(-1, -1);
    #pragma unroll
    for (int e = 0; e < EE; ++e) { c0[l][e] = 0; cA[l][e] = 0; }
    __syncthreads();

    const int CH = BT / 64;
    int t0 = l * CH;

    for (int t = t0; t < t0 + CH; ++t) {
        int2 a = assign[t];
        c0[l][a.x]++; cA[l][a.x]++; cA[l][a.y]++;
    }
    __syncthreads();

    #pragma unroll
    for (int e = 0; e < EE; ++e) {
        int v = c0[l][e], inc = v;
        for (int d = 1; d < 64; d <<= 1) { int u = __shfl_up(inc, d); if (l >= d) inc += u; }
        c0[l][e] = inc - v;
        v = cA[l][e]; inc = v;
        for (int d = 1; d < 64; d <<= 1) { int u = __shfl_up(inc, d); if (l >= d) inc += u; }
        cA[l][e] = inc - v;
    }
    __syncthreads();

    for (int t = t0; t < t0 + CH; ++t) {
        int2 a = assign[t];
        int p0 = ++c0[l][a.x];  cA[l][a.x]++;
        int p1 = ++cA[l][a.y];
        int4 m;
        m.x = a.x; m.y = (p0 < CAP) ? p0 : -1;
        m.z = a.y; m.w = (p1 < CAP) ? p1 : -1;
        meta[t] = m;
        int* st = (int*)slot_tok;
        if (p0 < CAP) st[(a.x * CAP + p0) * 2 + 0] = t;
        if (p1 < CAP) st[(a.y * CAP + p1) * 2 + 1] = t;
    }
}

// ---------------------------------------------------------------------------
// 3. Gather -> bf16 grouped (E, CAP, DD)
// ---------------------------------------------------------------------------
__global__ __launch_bounds__(256) void gather_bf16(
    const float* __restrict__ x, const int2* __restrict__ slot_tok,
    u16* __restrict__ G)
{
    int es = blockIdx.x;
    int d  = threadIdx.x * 4;
    int2 st = slot_tok[es];
    float4 r = make_float4(0.f, 0.f, 0.f, 0.f);
    if (st.x >= 0) r = *(const float4*)(x + (size_t)st.x * DD + d);
    if (st.y >= 0) {
        float4 v = *(const float4*)(x + (size_t)st.y * DD + d);
        r.x += v.x; r.y += v.y; r.z += v.z; r.w += v.w;
    }
    u16x4 o;
    o[0] = f2bf(r.x); o[1] = f2bf(r.y); o[2] = f2bf(r.z); o[3] = f2bf(r.w);
    *(u16x4*)(G + (size_t)es * DD + d) = o;
}

// ---------------------------------------------------------------------------
// LDS layouts:
//  A tile (bf16, K-contig source): 8 chunks x (16 rows x 64 B); linear
//    global_load_lds dest + pre-swizzled SOURCE k-slot, read slot
//    lq ^ ((row>>1)&3)  [verified round 4].
//  B tile (from fp32 natural (k rows, n cols)): pairs-interleaved bf16:
//    element (n, k-chunk s of 8) at byte (n>>1)*128 + ((2s+(n&1)) ^ ((n>>1)&7))*16.
//    Writes: one ds_write_b128 per (thread, column) -> 8 positions x 8 lanes
//    = bank floor. Reads: each 16-lane quarter-wave hits every position 2x = free.
// ---------------------------------------------------------------------------

// ---------------------------------------------------------------------------
// 5. GEMM1 (MFMA): H = gelu((G@w1)*(G@w2)) ; tiles 128x128, BK=32
//    A = grouped bf16 (CAP,DD); W1/W2 = natural fp32 (DD rows, HH cols)
// ---------------------------------------------------------------------------
__global__ __launch_bounds__(256, 2) void gemm1_mfma(
    const u16* __restrict__ G, const float* __restrict__ W1,
    const float* __restrict__ W2, u16* __restrict__ H)
{
    __shared__ u16 As [128 * 32];
    __shared__ u16 B1s[128 * 32];
    __shared__ u16 B2s[128 * 32];

    const int e  = blockIdx.z;
    const int n0 = blockIdx.x * 128;
    const int m0 = blockIdx.y * 128;
    const int tid  = threadIdx.x;
    const int lane = tid & 63;
    const int w    = tid >> 6;
    const int wr = w >> 1, wc = w & 1;
    const int lr = lane & 15, lq = lane >> 4;

    const char*  Ab  = (const char*)(G + (size_t)e * CAP * DD + (size_t)m0 * DD);
    const float* W1e = W1 + (size_t)e * DD * HH + n0;
    const float* W2e = W2 + (size_t)e * DD * HH + n0;

    const int srow = lane >> 2;                                  // A: row in chunk
    const int skb  = ((lane & 3) ^ ((lane >> 3) & 3)) * 16;      // A: pre-swizzled k-slot

    // B staging coords: thread covers 8k x 2n micro-tile
    const int np = tid & 63;       // n-pair index (n = 2np, 2np+1)
    const int sk = tid >> 6;       // k-chunk (8 k)
    const float* b1p = W1e + (size_t)sk * 8 * HH + 2 * np;
    const float* b2p = W2e + (size_t)sk * 8 * HH + 2 * np;
    const int wb0 = np * 128 + ((2 * sk + 0) ^ (np & 7)) * 16;
    const int wb1 = np * 128 + ((2 * sk + 1) ^ (np & 7)) * 16;

    f32x4 acc1[4][4] = {};
    f32x4 acc2[4][4] = {};

    for (int k0 = 0; k0 < DD; k0 += 32) {
        // ---- A staging (async direct-to-LDS) ----
        {
            const size_t kbyte = (size_t)k0 * 2 + skb;
            #pragma unroll
            for (int c2 = 0; c2 < 2; ++c2) {
                const int c = 2 * w + c2;
                const size_t rb = (size_t)(c * 16 + srow) * (DD * 2) + kbyte;
                __builtin_amdgcn_global_load_lds((const AS1 void*)(Ab + rb),
                    (AS3 void*)((char*)As + c * 1024), 16, 0, 0);
            }
        }
        // ---- B staging: fp32 natural -> bf16 transposed LDS ----
        {
            const float* p1 = b1p + (size_t)k0 * HH;
            const float* p2 = b2p + (size_t)k0 * HH;
            float2 v1[8], v2[8];
            #pragma unroll
            for (int kk = 0; kk < 8; ++kk) v1[kk] = *(const float2*)(p1 + (size_t)kk * HH);
            #pragma unroll
            for (int kk = 0; kk < 8; ++kk) v2[kk] = *(const float2*)(p2 + (size_t)kk * HH);
            u32x4 c0v, c1v;
            c0v[0] = pkbf(v1[0].x, v1[1].x); c0v[1] = pkbf(v1[2].x, v1[3].x);
            c0v[2] = pkbf(v1[4].x, v1[5].x); c0v[3] = pkbf(v1[6].x, v1[7].x);
            c1v[0] = pkbf(v1[0].y, v1[1].y); c1v[1] = pkbf(v1[2].y, v1[3].y);
            c1v[2] = pkbf(v1[4].y, v1[5].y); c1v[3] = pkbf(v1[6].y, v1[7].y);
            *(u32x4*)((char*)B1s + wb0) = c0v;
            *(u32x4*)((char*)B1s + wb1) = c1v;
            c0v[0] = pkbf(v2[0].x, v2[1].x); c0v[1] = pkbf(v2[2].x, v2[3].x);
            c0v[2] = pkbf(v2[4].x, v2[5].x); c0v[3] = pkbf(v2[6].x, v2[7].x);
            c1v[0] = pkbf(v2[0].y, v2[1].y); c1v[1] = pkbf(v2[2].y, v2[3].y);
            c1v[2] = pkbf(v2[4].y, v2[5].y); c1v[3] = pkbf(v2[6].y, v2[7].y);
            *(u32x4*)((char*)B2s + wb0) = c0v;
            *(u32x4*)((char*)B2s + wb1) = c1v;
        }
        __syncthreads();
        bf16x8 av[4], b1v[4], b2v[4];
        #pragma unroll
        for (int m = 0; m < 4; ++m) {
            const int row = wr * 64 + m * 16 + lr;
            const int sl  = (lq ^ ((row >> 1) & 3)) * 16;
            av[m] = *(const bf16x8*)((const char*)As + row * 64 + sl);
        }
        #pragma unroll
        for (int n = 0; n < 4; ++n) {
            const int nn = wc * 64 + n * 16 + lr;
            const int bo = (nn >> 1) * 128 + ((2 * lq + (nn & 1)) ^ ((nn >> 1) & 7)) * 16;
            b1v[n] = *(const bf16x8*)((const char*)B1s + bo);
            b2v[n] = *(const bf16x8*)((const char*)B2s + bo);
        }
        #pragma unroll
        for (int m = 0; m < 4; ++m)
            #pragma unroll
            for (int n = 0; n < 4; ++n) {
                acc1[m][n] = __builtin_amdgcn_mfma_f32_16x16x32_bf16(av[m], b1v[n], acc1[m][n], 0, 0, 0);
                acc2[m][n] = __builtin_amdgcn_mfma_f32_16x16x32_bf16(av[m], b2v[n], acc2[m][n], 0, 0, 0);
            }
        __syncthreads();
    }

    u16* He = H + (size_t)e * CAP * HH;
    const int r0 = m0 + wr * 64 + lq * 4;
    const int c0 = n0 + wc * 64 + lr;
    const float gc0 = 0.7978845608028654f, gc1 = 0.044715f;
    #pragma unroll
    for (int m = 0; m < 4; ++m)
        #pragma unroll
        for (int n = 0; n < 4; ++n)
            #pragma unroll
            for (int r = 0; r < 4; ++r) {
                float hv = acc1[m][n][r] * acc2[m][n][r];
                float u  = gc0 * (hv + gc1 * hv * hv * hv);
                float th = 1.f - 2.f / (__expf(2.f * u) + 1.f);   // tanh(u)
                He[(size_t)(r0 + m*16 + r) * HH + (c0 + n*16)] = f2bf(0.5f * hv * (1.f + th));
            }
}

// ---------------------------------------------------------------------------
// 6. GEMM2 (MFMA): EO = H @ w3 ; A = H bf16 (CAP,HH); W3 natural fp32 (HH,DD)
// ---------------------------------------------------------------------------
__global__ __launch_bounds__(256, 2) void gemm2_mfma(
    const u16* __restrict__ Hin, const float* __restrict__ W3, u16* __restrict__ EO)
{
    __shared__ u16 As[128 * 32];
    __shared__ u16 Bs[128 * 32];

    const int e  = blockIdx.z;
    const int n0 = blockIdx.x * 128;
    const int m0 = blockIdx.y * 128;
    const int tid  = threadIdx.x;
    const int lane = tid & 63;
    const int w    = tid >> 6;
    const int wr = w >> 1, wc = w & 1;
    const int lr = lane & 15, lq = lane >> 4;

    const char*  Ab  = (const char*)(Hin + (size_t)e * CAP * HH + (size_t)m0 * HH);
    const float* W3e = W3 + (size_t)e * HH * DD + n0;

    const int srow = lane >> 2;
    const int skb  = ((lane & 3) ^ ((lane >> 3) & 3)) * 16;

    const int np = tid & 63;
    const int sk = tid >> 6;
    const float* b3p = W3e + (size_t)sk * 8 * DD + 2 * np;
    const int wb0 = np * 128 + ((2 * sk + 0) ^ (np & 7)) * 16;
    const int wb1 = np * 128 + ((2 * sk + 1) ^ (np & 7)) * 16;

    f32x4 acc[4][4] = {};

    for (int k0 = 0; k0 < HH; k0 += 32) {
        {
            const size_t kbyte = (size_t)k0 * 2 + skb;
            #pragma unroll
            for (int c2 = 0; c2 < 2; ++c2) {
                const int c = 2 * w + c2;
                const size_t rb = (size_t)(c * 16 + srow) * (HH * 2) + kbyte;
                __builtin_amdgcn_global_load_lds((const AS1 void*)(Ab + rb),
                    (AS3 void*)((char*)As + c * 1024), 16, 0, 0);
            }
        }
        {
            const float* p3 = b3p + (size_t)k0 * DD;
            float2 v3[8];
            #pragma unroll
            for (int kk = 0; kk < 8; ++kk) v3[kk] = *(const float2*)(p3 + (size_t)kk * DD);
            u32x4 c0v, c1v;
            c0v[0] = pkbf(v3[0].x, v3[1].x); c0v[1] = pkbf(v3[2].x, v3[3].x);
            c0v[2] = pkbf(v3[4].x, v3[5].x); c0v[3] = pkbf(v3[6].x, v3[7].x);
            c1v[0] = pkbf(v3[0].y, v3[1].y); c1v[1] = pkbf(v3[2].y, v3[3].y);
            c1v[2] = pkbf(v3[4].y, v3[5].y); c1v[3] = pkbf(v3[6].y, v3[7].y);
            *(u32x4*)((char*)Bs + wb0) = c0v;
            *(u32x4*)((char*)Bs + wb1) = c1v;
        }
        __syncthreads();
        bf16x8 av[4], bv[4];
        #pragma unroll
        for (int m = 0; m < 4; ++m) {
            const int row = wr * 64 + m * 16 + lr;
            const int sl  = (lq ^ ((row >> 1) & 3)) * 16;
            av[m] = *(const bf16x8*)((const char*)As + row * 64 + sl);
        }
        #pragma unroll
        for (int n = 0; n < 4; ++n) {
            const int nn = wc * 64 + n * 16 + lr;
            const int bo = (nn >> 1) * 128 + ((2 * lq + (nn & 1)) ^ ((nn >> 1) & 7)) * 16;
            bv[n] = *(const bf16x8*)((const char*)Bs + bo);
        }
        #pragma unroll
        for (int m = 0; m < 4; ++m)
            #pragma unroll
            for (int n = 0; n < 4; ++n)
                acc[m][n] = __builtin_amdgcn_mfma_f32_16x16x32_bf16(av[m], bv[n], acc[m][n], 0, 0, 0);
        __syncthreads();
    }

    u16* Oe = EO + (size_t)e * CAP * DD;
    const int r0 = m0 + wr * 64 + lq * 4;
    const int c0 = n0 + wc * 64 + lr;
    #pragma unroll
    for (int m = 0; m < 4; ++m)
        #pragma unroll
        for (int n = 0; n < 4; ++n)
            #pragma unroll
            for (int r = 0; r < 4; ++r)
                Oe[(size_t)(r0 + m*16 + r) * DD + (c0 + n*16)] = f2bf(acc[m][n][r]);
}

// ---------------------------------------------------------------------------
// 7. Combine: out[t] = g0*(kept0 ? EO[e0][p0] : x) + g1*(...)   (EO is bf16)
// ---------------------------------------------------------------------------
__global__ __launch_bounds__(256) void combine_kernel(
    const float* __restrict__ x, const u16* __restrict__ EO,
    const int4* __restrict__ meta, const float2* __restrict__ gates,
    float* __restrict__ out)
{
    int t = blockIdx.x;
    int d = threadIdx.x * 4;
    int4  m = meta[t];
    float2 g = gates[t];
    float4 xv = *(const float4*)(x + (size_t)t * DD + d);
    float4 v0 = xv, v1 = xv;
    if (m.y >= 0) {
        u16x4 q = *(const u16x4*)(EO + ((size_t)m.x * CAP + m.y) * DD + d);
        v0 = make_float4(bf2f(q[0]), bf2f(q[1]), bf2f(q[2]), bf2f(q[3]));
    }
    if (m.w >= 0) {
        u16x4 q = *(const u16x4*)(EO + ((size_t)m.z * CAP + m.w) * DD + d);
        v1 = make_float4(bf2f(q[0]), bf2f(q[1]), bf2f(q[2]), bf2f(q[3]));
    }
    float4 r;
    r.x = g.x * v0.x + g.y * v1.x;
    r.y = g.x * v0.y + g.y * v1.y;
    r.z = g.x * v0.z + g.y * v1.z;
    r.w = g.x * v0.w + g.y * v1.w;
    *(float4*)(out + (size_t)t * DD + d) = r;
}

// ---------------------------------------------------------------------------
extern "C" void kernel_launch(void* const* d_in, const int* in_sizes, int n_in,
                              void* d_out, int out_size, void* d_ws, size_t ws_size,
                              hipStream_t stream)
{
    const float* x  = (const float*)d_in[0];
    const float* rw = (const float*)d_in[1];
    const float* rb = (const float*)d_in[2];
    const float* w1 = (const float*)d_in[3];
    const float* w2 = (const float*)d_in[4];
    const float* w3 = (const float*)d_in[5];
    float* out = (float*)d_out;

    char* ws = (char*)d_ws;
    size_t off = 0;
    auto alloc = [&](size_t bytes) { char* p = ws + off; off = (off + bytes + 255) & ~(size_t)255; return p; };

    int2*   assign   = (int2*)  alloc(BT * sizeof(int2));
    float2* gates    = (float2*)alloc(BT * sizeof(float2));
    int4*   meta     = (int4*)  alloc(BT * sizeof(int4));
    int2*   slot_tok = (int2*)  alloc(EE * CAP * sizeof(int2));
    u16*    grouped  = (u16*)   alloc((size_t)EE * CAP * DD * 2);   //  8.4 MB
    u16*    Hbuf     = (u16*)   alloc((size_t)EE * CAP * HH * 2);   // 16.8 MB
    u16*    eo       = (u16*)   alloc((size_t)EE * CAP * DD * 2);   //  8.4 MB
    (void)ws_size;

    router_kernel<<<BT, 256, 0, stream>>>(x, rw, rb, assign, gates);
    scan_kernel<<<1, 64, 0, stream>>>(assign, meta, slot_tok);
    gather_bf16<<<EE * CAP, 256, 0, stream>>>(x, slot_tok, grouped);

    gemm1_mfma<<<dim3(HH / 128, CAP / 128, EE), 256, 0, stream>>>(grouped, w1, w2, Hbuf);
    gemm2_mfma<<<dim3(DD / 128, CAP / 128, EE), 256, 0, stream>>>(Hbuf, w3, eo);

    combine_kernel<<<BT, 256, 0, stream>>>(x, eo, meta, gates, out);
}

// Round 6
// 168.301 us; speedup vs baseline: 4.3918x; 1.0246x over previous
//
#include <hip/hip_runtime.h>
#include <hip/hip_bf16.h>
#include <math.h>

// Problem constants
#define BT   2048      // B*T tokens
#define DD   1024      // model dim
#define HH   2048      // hidden dim
#define EE   8         // experts
#define CAP  512       // expert capacity = floor(BT*0.25)

typedef unsigned short u16;
typedef unsigned int   u32;
typedef short bf16x8 __attribute__((ext_vector_type(8)));   // 8 bf16 (4 VGPRs) MFMA frag
typedef float f32x4  __attribute__((ext_vector_type(4)));   // MFMA accumulator
typedef u16   u16x4  __attribute__((ext_vector_type(4)));
typedef u16   u16x8  __attribute__((ext_vector_type(8)));
typedef u32   u32x4  __attribute__((ext_vector_type(4)));

#define AS1 __attribute__((address_space(1)))
#define AS3 __attribute__((address_space(3)))

__device__ __forceinline__ u16 f2bf(float f) {   // RNE fp32->bf16
    union { float f; u32 u; } v; v.f = f;
    return (u16)((v.u + 0x7fffu + ((v.u >> 16) & 1u)) >> 16);
}
__device__ __forceinline__ float bf2f(u16 b) {   // exact bf16->fp32
    union { u32 u; float f; } v; v.u = ((u32)b) << 16;
    return v.f;
}
// pack two fp32 -> two bf16 in one u32 (RNE), gfx950 HW instr (no builtin)
__device__ __forceinline__ u32 pkbf(float lo, float hi) {
    u32 r;
    asm("v_cvt_pk_bf16_f32 %0, %1, %2" : "=v"(r) : "v"(lo), "v"(hi));
    return r;
}

// ---------------------------------------------------------------------------
// 1. Router (fp32, exact): scores = x @ rw + rb ; top-2 ; softmax gates
// ---------------------------------------------------------------------------
__global__ __launch_bounds__(256) void router_kernel(
    const float* __restrict__ x, const float* __restrict__ rw,
    const float* __restrict__ rb, int2* __restrict__ assign,
    float2* __restrict__ gates)
{
    int t   = blockIdx.x;
    int tid = threadIdx.x;
    const float* xr = x + (size_t)t * DD;

    float p[EE];
    #pragma unroll
    for (int e = 0; e < EE; ++e) p[e] = 0.f;

    for (int d = tid; d < DD; d += 256) {
        float xv = xr[d];
        const float4* wr = (const float4*)(rw + (size_t)d * EE);
        float4 w0 = wr[0], w1 = wr[1];
        p[0] += xv * w0.x; p[1] += xv * w0.y; p[2] += xv * w0.z; p[3] += xv * w0.w;
        p[4] += xv * w1.x; p[5] += xv * w1.y; p[6] += xv * w1.z; p[7] += xv * w1.w;
    }
    #pragma unroll
    for (int off = 32; off; off >>= 1) {
        #pragma unroll
        for (int e = 0; e < EE; ++e) p[e] += __shfl_down(p[e], off);
    }
    __shared__ float red[4][EE];
    int wv = tid >> 6, ln = tid & 63;
    if (ln == 0) {
        #pragma unroll
        for (int e = 0; e < EE; ++e) red[wv][e] = p[e];
    }
    __syncthreads();
    if (tid == 0) {
        float s[EE];
        #pragma unroll
        for (int e = 0; e < EE; ++e)
            s[e] = red[0][e] + red[1][e] + red[2][e] + red[3][e] + rb[e];
        int i0 = 0;
        #pragma unroll
        for (int e = 1; e < EE; ++e) if (s[e] > s[i0]) i0 = e;
        int i1 = -1;
        #pragma unroll
        for (int e = 0; e < EE; ++e) {
            if (e == i0) continue;
            if (i1 < 0 || s[e] > s[i1]) i1 = e;
        }
        float e1 = expf(s[i1] - s[i0]);
        float denom = 1.0f + e1;
        assign[t] = make_int2(i0, i1);
        gates[t]  = make_float2(1.0f / denom, e1 / denom);
    }
}

// ---------------------------------------------------------------------------
// 2. Scan (exact reference cumsum semantics — verified round 1)
// ---------------------------------------------------------------------------
__global__ __launch_bounds__(64) void scan_kernel(
    const int2* __restrict__ assign, int4* __restrict__ meta,
    int2* __restrict__ slot_tok)
{
    __shared__ int c0[64][EE];
    __shared__ int cA[64][EE];
    int l = threadIdx.x;

    for (int i = l; i < EE * CAP; i += 64) slot_tok[i] = make_int2(-1, -1);
    #pragma unroll
    for (int e = 0; e < EE; ++e) { c0[l][e] = 0; cA[l][e] = 0; }
    __syncthreads();

    const int CH = BT / 64;
    int t0 = l * CH;

    for (int t = t0; t < t0 + CH; ++t) {
        int2 a = assign[t];
        c0[l][a.x]++; cA[l][a.x]++; cA[l][a.y]++;
    }
    __syncthreads();

    #pragma unroll
    for (int e = 0; e < EE; ++e) {
        int v = c0[l][e], inc = v;
        for (int d = 1; d < 64; d <<= 1) { int u = __shfl_up(inc, d); if (l >= d) inc += u; }
        c0[l][e] = inc - v;
        v = cA[l][e]; inc = v;
        for (int d = 1; d < 64; d <<= 1) { int u = __shfl_up(inc, d); if (l >= d) inc += u; }
        cA[l][e] = inc - v;
    }
    __syncthreads();

    for (int t = t0; t < t0 + CH; ++t) {
        int2 a = assign[t];
        int p0 = ++c0[l][a.x];  cA[l][a.x]++;
        int p1 = ++cA[l][a.y];
        int4 m;
        m.x = a.x; m.y = (p0 < CAP) ? p0 : -1;
        m.z = a.y; m.w = (p1 < CAP) ? p1 : -1;
        meta[t] = m;
        int* st = (int*)slot_tok;
        if (p0 < CAP) st[(a.x * CAP + p0) * 2 + 0] = t;
        if (p1 < CAP) st[(a.y * CAP + p1) * 2 + 1] = t;
    }
}

// ---------------------------------------------------------------------------
// 3. Gather -> bf16 grouped (E, CAP, DD)
// ---------------------------------------------------------------------------
__global__ __launch_bounds__(256) void gather_bf16(
    const float* __restrict__ x, const int2* __restrict__ slot_tok,
    u16* __restrict__ G)
{
    int es = blockIdx.x;
    int d  = threadIdx.x * 4;
    int2 st = slot_tok[es];
    float4 r = make_float4(0.f, 0.f, 0.f, 0.f);
    if (st.x >= 0) r = *(const float4*)(x + (size_t)st.x * DD + d);
    if (st.y >= 0) {
        float4 v = *(const float4*)(x + (size_t)st.y * DD + d);
        r.x += v.x; r.y += v.y; r.z += v.z; r.w += v.w;
    }
    u16x4 o;
    o[0] = f2bf(r.x); o[1] = f2bf(r.y); o[2] = f2bf(r.z); o[3] = f2bf(r.w);
    *(u16x4*)(G + (size_t)es * DD + d) = o;
}

// ---------------------------------------------------------------------------
// LDS layouts (verified round 4/5):
//  A: 8 chunks x (16 rows x 64 B); linear global_load_lds dest, pre-swizzled
//     SOURCE k-slot, read slot lq ^ ((row>>1)&3).
//  B: pairs-interleaved bf16: elem (n, k-chunk s) at byte
//     (n>>1)*128 + ((2s+(n&1)) ^ ((n>>1)&7))*16.
// Pipeline (T14): single barrier per K-step + dbuf LDS; B-reg gloads and
// A-DMA for tile k+1 issued AFTER the barrier, so they fly under MFMA(k)
// and are consumed by pack(k+1) / frag-reads(k+1) one iteration later.
// ---------------------------------------------------------------------------

// ---------------------------------------------------------------------------
// 5. GEMM1 (MFMA): H = gelu((G@w1)*(G@w2)) ; tiles 128x128, BK=32
// ---------------------------------------------------------------------------
__global__ __launch_bounds__(256, 2) void gemm1_mfma(
    const u16* __restrict__ G, const float* __restrict__ W1,
    const float* __restrict__ W2, u16* __restrict__ H)
{
    __shared__ u16 As [2][128 * 32];
    __shared__ u16 B1s[2][128 * 32];
    __shared__ u16 B2s[2][128 * 32];

    const int e  = blockIdx.z;
    const int n0 = blockIdx.x * 128;
    const int m0 = blockIdx.y * 128;
    const int tid  = threadIdx.x;
    const int lane = tid & 63;
    const int w    = tid >> 6;
    const int wr = w >> 1, wc = w & 1;
    const int lr = lane & 15, lq = lane >> 4;

    const char*  Ab  = (const char*)(G + (size_t)e * CAP * DD + (size_t)m0 * DD);
    const float* W1e = W1 + (size_t)e * DD * HH + n0;
    const float* W2e = W2 + (size_t)e * DD * HH + n0;

    const int srow = lane >> 2;                                  // A: row in chunk
    const int skb  = ((lane & 3) ^ ((lane >> 3) & 3)) * 16;      // A: pre-swizzled k-slot

    // B staging coords: thread covers 8k x 2n micro-tile
    const int np = tid & 63;       // n-pair index
    const int sk = tid >> 6;       // k-chunk (8 k)
    const float* b1p = W1e + (size_t)sk * 8 * HH + 2 * np;
    const float* b2p = W2e + (size_t)sk * 8 * HH + 2 * np;
    const int wb0 = np * 128 + ((2 * sk + 0) ^ (np & 7)) * 16;
    const int wb1 = np * 128 + ((2 * sk + 1) ^ (np & 7)) * 16;

    f32x4 acc1[4][4] = {};
    f32x4 acc2[4][4] = {};

    float2 v1[8], v2[8];
    // ---- prologue: B-reg loads + A-DMA for tile 0 ----
    {
        #pragma unroll
        for (int kk = 0; kk < 8; ++kk) v1[kk] = *(const float2*)(b1p + (size_t)kk * HH);
        #pragma unroll
        for (int kk = 0; kk < 8; ++kk) v2[kk] = *(const float2*)(b2p + (size_t)kk * HH);
        #pragma unroll
        for (int c2 = 0; c2 < 2; ++c2) {
            const int c = 2 * w + c2;
            const size_t rb = (size_t)(c * 16 + srow) * (DD * 2) + skb;
            __builtin_amdgcn_global_load_lds((const AS1 void*)(Ab + rb),
                (AS3 void*)((char*)As[0] + c * 1024), 16, 0, 0);
        }
    }

    const int NT = DD / 32;
    for (int it = 0; it < NT; ++it) {
        const int cur = it & 1;
        // ---- pack + ds_write tile it (waits on its B-reg loads) ----
        {
            char* B1c = (char*)B1s[cur];
            char* B2c = (char*)B2s[cur];
            u32x4 c0v, c1v;
            c0v[0] = pkbf(v1[0].x, v1[1].x); c0v[1] = pkbf(v1[2].x, v1[3].x);
            c0v[2] = pkbf(v1[4].x, v1[5].x); c0v[3] = pkbf(v1[6].x, v1[7].x);
            c1v[0] = pkbf(v1[0].y, v1[1].y); c1v[1] = pkbf(v1[2].y, v1[3].y);
            c1v[2] = pkbf(v1[4].y, v1[5].y); c1v[3] = pkbf(v1[6].y, v1[7].y);
            *(u32x4*)(B1c + wb0) = c0v;
            *(u32x4*)(B1c + wb1) = c1v;
            c0v[0] = pkbf(v2[0].x, v2[1].x); c0v[1] = pkbf(v2[2].x, v2[3].x);
            c0v[2] = pkbf(v2[4].x, v2[5].x); c0v[3] = pkbf(v2[6].x, v2[7].x);
            c1v[0] = pkbf(v2[0].y, v2[1].y); c1v[1] = pkbf(v2[2].y, v2[3].y);
            c1v[2] = pkbf(v2[4].y, v2[5].y); c1v[3] = pkbf(v2[6].y, v2[7].y);
            *(u32x4*)(B2c + wb0) = c0v;
            *(u32x4*)(B2c + wb1) = c1v;
        }
        __syncthreads();
        // ---- issue staging for tile it+1 (flies under MFMA below) ----
        if (it + 1 < NT) {
            const size_t koff = (size_t)(it + 1) * 32;
            const float* p1 = b1p + koff * HH;
            const float* p2 = b2p + koff * HH;
            #pragma unroll
            for (int kk = 0; kk < 8; ++kk) v1[kk] = *(const float2*)(p1 + (size_t)kk * HH);
            #pragma unroll
            for (int kk = 0; kk < 8; ++kk) v2[kk] = *(const float2*)(p2 + (size_t)kk * HH);
            const size_t kbyte = koff * 2 + skb;
            #pragma unroll
            for (int c2 = 0; c2 < 2; ++c2) {
                const int c = 2 * w + c2;
                const size_t rb = (size_t)(c * 16 + srow) * (DD * 2) + kbyte;
                __builtin_amdgcn_global_load_lds((const AS1 void*)(Ab + rb),
                    (AS3 void*)((char*)As[cur ^ 1] + c * 1024), 16, 0, 0);
            }
        }
        // ---- frag reads + MFMA on tile it ----
        bf16x8 av[4], b1v[4], b2v[4];
        #pragma unroll
        for (int m = 0; m < 4; ++m) {
            const int row = wr * 64 + m * 16 + lr;
            const int sl  = (lq ^ ((row >> 1) & 3)) * 16;
            av[m] = *(const bf16x8*)((const char*)As[cur] + row * 64 + sl);
        }
        #pragma unroll
        for (int n = 0; n < 4; ++n) {
            const int nn = wc * 64 + n * 16 + lr;
            const int bo = (nn >> 1) * 128 + ((2 * lq + (nn & 1)) ^ ((nn >> 1) & 7)) * 16;
            b1v[n] = *(const bf16x8*)((const char*)B1s[cur] + bo);
            b2v[n] = *(const bf16x8*)((const char*)B2s[cur] + bo);
        }
        #pragma unroll
        for (int m = 0; m < 4; ++m)
            #pragma unroll
            for (int n = 0; n < 4; ++n) {
                acc1[m][n] = __builtin_amdgcn_mfma_f32_16x16x32_bf16(av[m], b1v[n], acc1[m][n], 0, 0, 0);
                acc2[m][n] = __builtin_amdgcn_mfma_f32_16x16x32_bf16(av[m], b2v[n], acc2[m][n], 0, 0, 0);
            }
    }

    u16* He = H + (size_t)e * CAP * HH;
    const int r0 = m0 + wr * 64 + lq * 4;
    const int c0 = n0 + wc * 64 + lr;
    const float gc0 = 0.7978845608028654f, gc1 = 0.044715f;
    #pragma unroll
    for (int m = 0; m < 4; ++m)
        #pragma unroll
        for (int n = 0; n < 4; ++n)
            #pragma unroll
            for (int r = 0; r < 4; ++r) {
                float hv = acc1[m][n][r] * acc2[m][n][r];
                float u  = gc0 * (hv + gc1 * hv * hv * hv);
                float th = 1.f - 2.f / (__expf(2.f * u) + 1.f);   // tanh(u)
                He[(size_t)(r0 + m*16 + r) * HH + (c0 + n*16)] = f2bf(0.5f * hv * (1.f + th));
            }
}

// ---------------------------------------------------------------------------
// 6. GEMM2 (MFMA): EO = H @ w3 ; A = H bf16 (CAP,HH); W3 natural fp32 (HH,DD)
// ---------------------------------------------------------------------------
__global__ __launch_bounds__(256, 2) void gemm2_mfma(
    const u16* __restrict__ Hin, const float* __restrict__ W3, u16* __restrict__ EO)
{
    __shared__ u16 As[2][128 * 32];
    __shared__ u16 Bs[2][128 * 32];

    const int e  = blockIdx.z;
    const int n0 = blockIdx.x * 128;
    const int m0 = blockIdx.y * 128;
    const int tid  = threadIdx.x;
    const int lane = tid & 63;
    const int w    = tid >> 6;
    const int wr = w >> 1, wc = w & 1;
    const int lr = lane & 15, lq = lane >> 4;

    const char*  Ab  = (const char*)(Hin + (size_t)e * CAP * HH + (size_t)m0 * HH);
    const float* W3e = W3 + (size_t)e * HH * DD + n0;

    const int srow = lane >> 2;
    const int skb  = ((lane & 3) ^ ((lane >> 3) & 3)) * 16;

    const int np = tid & 63;
    const int sk = tid >> 6;
    const float* b3p = W3e + (size_t)sk * 8 * DD + 2 * np;
    const int wb0 = np * 128 + ((2 * sk + 0) ^ (np & 7)) * 16;
    const int wb1 = np * 128 + ((2 * sk + 1) ^ (np & 7)) * 16;

    f32x4 acc[4][4] = {};

    float2 v3[8];
    {
        #pragma unroll
        for (int kk = 0; kk < 8; ++kk) v3[kk] = *(const float2*)(b3p + (size_t)kk * DD);
        #pragma unroll
        for (int c2 = 0; c2 < 2; ++c2) {
            const int c = 2 * w + c2;
            const size_t rb = (size_t)(c * 16 + srow) * (HH * 2) + skb;
            __builtin_amdgcn_global_load_lds((const AS1 void*)(Ab + rb),
                (AS3 void*)((char*)As[0] + c * 1024), 16, 0, 0);
        }
    }

    const int NT = HH / 32;
    for (int it = 0; it < NT; ++it) {
        const int cur = it & 1;
        {
            char* Bc = (char*)Bs[cur];
            u32x4 c0v, c1v;
            c0v[0] = pkbf(v3[0].x, v3[1].x); c0v[1] = pkbf(v3[2].x, v3[3].x);
            c0v[2] = pkbf(v3[4].x, v3[5].x); c0v[3] = pkbf(v3[6].x, v3[7].x);
            c1v[0] = pkbf(v3[0].y, v3[1].y); c1v[1] = pkbf(v3[2].y, v3[3].y);
            c1v[2] = pkbf(v3[4].y, v3[5].y); c1v[3] = pkbf(v3[6].y, v3[7].y);
            *(u32x4*)(Bc + wb0) = c0v;
            *(u32x4*)(Bc + wb1) = c1v;
        }
        __syncthreads();
        if (it + 1 < NT) {
            const size_t koff = (size_t)(it + 1) * 32;
            const float* p3 = b3p + koff * DD;
            #pragma unroll
            for (int kk = 0; kk < 8; ++kk) v3[kk] = *(const float2*)(p3 + (size_t)kk * DD);
            const size_t kbyte = koff * 2 + skb;
            #pragma unroll
            for (int c2 = 0; c2 < 2; ++c2) {
                const int c = 2 * w + c2;
                const size_t rb = (size_t)(c * 16 + srow) * (HH * 2) + kbyte;
                __builtin_amdgcn_global_load_lds((const AS1 void*)(Ab + rb),
                    (AS3 void*)((char*)As[cur ^ 1] + c * 1024), 16, 0, 0);
            }
        }
        bf16x8 av[4], bv[4];
        #pragma unroll
        for (int m = 0; m < 4; ++m) {
            const int row = wr * 64 + m * 16 + lr;
            const int sl  = (lq ^ ((row >> 1) & 3)) * 16;
            av[m] = *(const bf16x8*)((const char*)As[cur] + row * 64 + sl);
        }
        #pragma unroll
        for (int n = 0; n < 4; ++n) {
            const int nn = wc * 64 + n * 16 + lr;
            const int bo = (nn >> 1) * 128 + ((2 * lq + (nn & 1)) ^ ((nn >> 1) & 7)) * 16;
            bv[n] = *(const bf16x8*)((const char*)Bs[cur] + bo);
        }
        #pragma unroll
        for (int m = 0; m < 4; ++m)
            #pragma unroll
            for (int n = 0; n < 4; ++n)
                acc[m][n] = __builtin_amdgcn_mfma_f32_16x16x32_bf16(av[m], bv[n], acc[m][n], 0, 0, 0);
    }

    u16* Oe = EO + (size_t)e * CAP * DD;
    const int r0 = m0 + wr * 64 + lq * 4;
    const int c0 = n0 + wc * 64 + lr;
    #pragma unroll
    for (int m = 0; m < 4; ++m)
        #pragma unroll
        for (int n = 0; n < 4; ++n)
            #pragma unroll
            for (int r = 0; r < 4; ++r)
                Oe[(size_t)(r0 + m*16 + r) * DD + (c0 + n*16)] = f2bf(acc[m][n][r]);
}

// ---------------------------------------------------------------------------
// 7. Combine: out[t] = g0*(kept0 ? EO[e0][p0] : x) + g1*(...)   (EO is bf16)
// ---------------------------------------------------------------------------
__global__ __launch_bounds__(256) void combine_kernel(
    const float* __restrict__ x, const u16* __restrict__ EO,
    const int4* __restrict__ meta, const float2* __restrict__ gates,
    float* __restrict__ out)
{
    int t = blockIdx.x;
    int d = threadIdx.x * 4;
    int4  m = meta[t];
    float2 g = gates[t];
    float4 xv = *(const float4*)(x + (size_t)t * DD + d);
    float4 v0 = xv, v1 = xv;
    if (m.y >= 0) {
        u16x4 q = *(const u16x4*)(EO + ((size_t)m.x * CAP + m.y) * DD + d);
        v0 = make_float4(bf2f(q[0]), bf2f(q[1]), bf2f(q[2]), bf2f(q[3]));
    }
    if (m.w >= 0) {
        u16x4 q = *(const u16x4*)(EO + ((size_t)m.z * CAP + m.w) * DD + d);
        v1 = make_float4(bf2f(q[0]), bf2f(q[1]), bf2f(q[2]), bf2f(q[3]));
    }
    float4 r;
    r.x = g.x * v0.x + g.y * v1.x;
    r.y = g.x * v0.y + g.y * v1.y;
    r.z = g.x * v0.z + g.y * v1.z;
    r.w = g.x * v0.w + g.y * v1.w;
    *(float4*)(out + (size_t)t * DD + d) = r;
}

// ---------------------------------------------------------------------------
extern "C" void kernel_launch(void* const* d_in, const int* in_sizes, int n_in,
                              void* d_out, int out_size, void* d_ws, size_t ws_size,
                              hipStream_t stream)
{
    const float* x  = (const float*)d_in[0];
    const float* rw = (const float*)d_in[1];
    const float* rb = (const float*)d_in[2];
    const float* w1 = (const float*)d_in[3];
    const float* w2 = (const float*)d_in[4];
    const float* w3 = (const float*)d_in[5];
    float* out = (float*)d_out;

    char* ws = (char*)d_ws;
    size_t off = 0;
    auto alloc = [&](size_t bytes) { char* p = ws + off; off = (off + bytes + 255) & ~(size_t)255; return p; };

    int2*   assign   = (int2*)  alloc(BT * sizeof(int2));
    float2* gates    = (float2*)alloc(BT * sizeof(float2));
    int4*   meta     = (int4*)  alloc(BT * sizeof(int4));
    int2*   slot_tok = (int2*)  alloc(EE * CAP * sizeof(int2));
    u16*    grouped  = (u16*)   alloc((size_t)EE * CAP * DD * 2);   //  8.4 MB
    u16*    Hbuf     = (u16*)   alloc((size_t)EE * CAP * HH * 2);   // 16.8 MB
    u16*    eo       = (u16*)   alloc((size_t)EE * CAP * DD * 2);   //  8.4 MB
    (void)ws_size;

    router_kernel<<<BT, 256, 0, stream>>>(x, rw, rb, assign, gates);
    scan_kernel<<<1, 64, 0, stream>>>(assign, meta, slot_tok);
    gather_bf16<<<EE * CAP, 256, 0, stream>>>(x, slot_tok, grouped);

    gemm1_mfma<<<dim3(HH / 128, CAP / 128, EE), 256, 0, stream>>>(grouped, w1, w2, Hbuf);
    gemm2_mfma<<<dim3(DD / 128, CAP / 128, EE), 256, 0, stream>>>(Hbuf, w3, eo);

    combine_kernel<<<BT, 256, 0, stream>>>(x, eo, meta, gates, out);
}